// Round 1
// baseline (1186.828 us; speedup 1.0000x reference)
//
#include <hip/hip_runtime.h>
#include <stdint.h>

typedef unsigned int uint;
typedef unsigned short u16;
typedef unsigned long long u64;

typedef float  f32x4 __attribute__((ext_vector_type(4)));
typedef uint   u32x4 __attribute__((ext_vector_type(4)));
typedef u16    u16x4 __attribute__((ext_vector_type(4)));
typedef u16    u16x8 __attribute__((ext_vector_type(8)));
typedef __bf16 bf16x8 __attribute__((ext_vector_type(8)));

#define DEV static __device__ __forceinline__
#define MFMA(a,b,c) __builtin_amdgcn_mfma_f32_16x16x32_bf16((a),(b),(c),0,0,0)

DEV u16 f2bf(float x){ union{float f;uint u;} v; v.f=x; return (u16)((v.u + 0x7fffu + ((v.u>>16)&1u))>>16); }
DEV float bf2f(u16 b){ union{uint u;float f;} v; v.u=((uint)b)<<16; return v.f; }

// ---------------- converts ----------------
__global__ void cvt_bf16_v4(const float* __restrict__ in, u16* __restrict__ out, int n4){
  int i = blockIdx.x*blockDim.x + threadIdx.x;
  int st = gridDim.x*blockDim.x;
  for(; i<n4; i+=st){
    f32x4 x = reinterpret_cast<const f32x4*>(in)[i];
    u16x4 y;
    #pragma unroll
    for(int j=0;j<4;j++) y[j] = f2bf(x[j]);
    reinterpret_cast<u16x4*>(out)[i] = y;
  }
}

__global__ void cvt_split_v4(const float* __restrict__ in, u16* __restrict__ hi, u16* __restrict__ lo, int n4){
  int i = blockIdx.x*blockDim.x + threadIdx.x;
  int st = gridDim.x*blockDim.x;
  for(; i<n4; i+=st){
    f32x4 x = reinterpret_cast<const f32x4*>(in)[i];
    u16x4 h, l;
    #pragma unroll
    for(int j=0;j<4;j++){
      u16 hb = f2bf(x[j]); h[j]=hb;
      l[j] = f2bf(x[j] - bf2f(hb));
    }
    reinterpret_cast<u16x4*>(hi)[i] = h;
    reinterpret_cast<u16x4*>(lo)[i] = l;
  }
}

// ---------------- generic NT GEMM: C[M,N] = alpha * A[M,K] * B[N,K]^T (+C) ----------------
__global__ __launch_bounds__(256,3) void gemm_nt(
    const u16* __restrict__ A, int lda,
    const u16* __restrict__ B, int ldb,
    float* __restrict__ C, int ldc,
    int M, int N, int K, float alpha, int accum)
{
  __shared__ u16 As[128*40];
  __shared__ u16 Bs[128*40];
  const int tid = threadIdx.x;
  const int w = tid>>6, l = tid&63;
  const int wr = w>>1, wc = w&1;
  const int l15 = l&15, l16 = l>>4;
  const int m0 = blockIdx.y*128, n0 = blockIdx.x*128;

  f32x4 acc[4][4];
  #pragma unroll
  for(int m=0;m<4;m++)
    #pragma unroll
    for(int n=0;n<4;n++) acc[m][n] = f32x4{0.f,0.f,0.f,0.f};

  int rowA[2], rowB[2], partk[2], rowi[2];
  u32x4 ra[2], rb[2];
  #pragma unroll
  for(int i=0;i<2;i++){
    int slot = tid + i*256;
    rowi[i] = slot>>2; partk[i] = (slot&3)*8;
    int ar = m0+rowi[i]; if(ar>=M) ar=M-1; rowA[i]=ar;
    int br = n0+rowi[i]; if(br>=N) br=N-1; rowB[i]=br;
  }
  #pragma unroll
  for(int i=0;i<2;i++){
    ra[i] = *reinterpret_cast<const u32x4*>(&A[(size_t)rowA[i]*lda + partk[i]]);
    rb[i] = *reinterpret_cast<const u32x4*>(&B[(size_t)rowB[i]*ldb + partk[i]]);
  }
  for(int k0=0;k0<K;k0+=32){
    __syncthreads();
    #pragma unroll
    for(int i=0;i<2;i++){
      *reinterpret_cast<u32x4*>(&As[rowi[i]*40 + partk[i]]) = ra[i];
      *reinterpret_cast<u32x4*>(&Bs[rowi[i]*40 + partk[i]]) = rb[i];
    }
    __syncthreads();
    int k1 = k0+32;
    if(k1 < K){
      #pragma unroll
      for(int i=0;i<2;i++){
        ra[i] = *reinterpret_cast<const u32x4*>(&A[(size_t)rowA[i]*lda + k1 + partk[i]]);
        rb[i] = *reinterpret_cast<const u32x4*>(&B[(size_t)rowB[i]*ldb + k1 + partk[i]]);
      }
    }
    bf16x8 a[4], b[4];
    #pragma unroll
    for(int m=0;m<4;m++) a[m] = *reinterpret_cast<const bf16x8*>(&As[(wr*64+m*16+l15)*40 + l16*8]);
    #pragma unroll
    for(int n=0;n<4;n++) b[n] = *reinterpret_cast<const bf16x8*>(&Bs[(wc*64+n*16+l15)*40 + l16*8]);
    #pragma unroll
    for(int m=0;m<4;m++)
      #pragma unroll
      for(int n=0;n<4;n++)
        acc[m][n] = MFMA(a[m], b[n], acc[m][n]);
  }
  #pragma unroll
  for(int m=0;m<4;m++){
    int row = m0 + wr*64 + m*16 + l16*4;
    #pragma unroll
    for(int n=0;n<4;n++){
      int col = n0 + wc*64 + n*16 + l15;
      if(col < N){
        #pragma unroll
        for(int r=0;r<4;r++){
          int rr = row + r;
          if(rr < M){
            float vv = alpha*acc[m][n][r];
            size_t ci = (size_t)rr*ldc + col;
            if(accum) vv += C[ci];
            C[ci] = vv;
          }
        }
      }
    }
  }
}

// ---------------- norms / rope ----------------
__global__ __launch_bounds__(256) void rmsnorm_qr_split(
    const float* __restrict__ in, const float* __restrict__ w,
    u16* __restrict__ hi, u16* __restrict__ lo)
{
  int s = blockIdx.x, tid = threadIdx.x;
  __shared__ float red[4];
  const float* x = in + (size_t)s*1536;
  float xv[6]; float ss=0.f;
  #pragma unroll
  for(int i=0;i<6;i++){ xv[i] = x[tid + i*256]; ss += xv[i]*xv[i]; }
  #pragma unroll
  for(int o=32;o>0;o>>=1) ss += __shfl_down(ss,o,64);
  if((tid&63)==0) red[tid>>6]=ss;
  __syncthreads();
  float total = red[0]+red[1]+red[2]+red[3];
  float scale = rsqrtf(total*(1.0f/1536.0f) + 1e-6f);
  #pragma unroll
  for(int i=0;i<6;i++){
    int c = tid + i*256;
    float vv = xv[i]*scale*w[c];
    u16 hv = f2bf(vv);
    hi[(size_t)s*1536+c]=hv;
    lo[(size_t)s*1536+c]=f2bf(vv - bf2f(hv));
  }
}

__global__ __launch_bounds__(256) void kv_norm_rope(
    const float* __restrict__ kvall, const float* __restrict__ w,
    const float* __restrict__ fcos, const float* __restrict__ fsin,
    u16* __restrict__ kvb, float* __restrict__ kpe)
{
  int s = blockIdx.x, tid = threadIdx.x;
  __shared__ float red[4];
  const float* x = kvall + (size_t)s*576;
  float xv[2]; float ss=0.f;
  #pragma unroll
  for(int i=0;i<2;i++){ xv[i]=x[tid+i*256]; ss+=xv[i]*xv[i]; }
  #pragma unroll
  for(int o=32;o>0;o>>=1) ss += __shfl_down(ss,o,64);
  if((tid&63)==0) red[tid>>6]=ss;
  __syncthreads();
  float total = red[0]+red[1]+red[2]+red[3];
  float scale = rsqrtf(total*(1.0f/512.0f)+1e-6f);
  #pragma unroll
  for(int i=0;i<2;i++){ int c=tid+i*256; kvb[(size_t)s*512+c]=f2bf(xv[i]*scale*w[c]); }
  if(tid<32){
    float c0=fcos[(size_t)s*32+tid], s_=fsin[(size_t)s*32+tid];
    float x0=x[512+2*tid], x1=x[513+2*tid];
    kpe[(size_t)s*64+2*tid]   = x0*c0 - x1*s_;
    kpe[(size_t)s*64+2*tid+1] = x0*s_ + x1*c0;
  }
}

__global__ __launch_bounds__(256) void rope_q_cvt(const float* __restrict__ qpre,
    const float* __restrict__ fcos, const float* __restrict__ fsin, u16* __restrict__ qb)
{
  int s = blockIdx.x;
  const float* rowp = qpre + (size_t)s*3072;
  u16* op = qb + (size_t)s*3072;
  for(int idx=threadIdx.x; idx<3072; idx+=256){
    int hh = idx/192, d = idx - hh*192;
    float vv;
    if(d < 128) vv = rowp[hh*192 + d];
    else{
      int i2 = (d-128)>>1;
      float c0 = fcos[(size_t)s*32+i2], s_ = fsin[(size_t)s*32+i2];
      float x0 = rowp[hh*192 + 128 + 2*i2], x1 = rowp[hh*192 + 129 + 2*i2];
      vv = ((d&1)==0) ? (x0*c0 - x1*s_) : (x0*s_ + x1*c0);
    }
    op[idx] = f2bf(vv);
  }
}

__global__ __launch_bounds__(256) void qi_rope_split(const float* __restrict__ qpre,
    const float* __restrict__ fcos, const float* __restrict__ fsin,
    u16* __restrict__ hi, u16* __restrict__ lo)
{
  int s = blockIdx.x;
  const float* rowp = qpre + (size_t)s*4096;
  for(int idx=threadIdx.x; idx<4096; idx+=256){
    int hh = idx>>7, d = idx&127;
    const float* hb = rowp + (hh<<7);
    float vv;
    if(d<32){ float c0=fcos[(size_t)s*32+d], s_=fsin[(size_t)s*32+d]; vv = hb[d]*c0 - hb[d+32]*s_; }
    else if(d<64){ int i2=d-32; float c0=fcos[(size_t)s*32+i2], s_=fsin[(size_t)s*32+i2]; vv = hb[i2]*s_ + hb[d]*c0; }
    else vv = hb[d];
    u16 hv = f2bf(vv);
    hi[(size_t)s*4096+idx]=hv;
    lo[(size_t)s*4096+idx]=f2bf(vv - bf2f(hv));
  }
}

__global__ __launch_bounds__(128) void ki_ln_rope_split(
    const float* __restrict__ kpre, const float* __restrict__ w, const float* __restrict__ bb,
    const float* __restrict__ fcos, const float* __restrict__ fsin,
    u16* __restrict__ hi, u16* __restrict__ lo)
{
  int s = blockIdx.x, tid = threadIdx.x;
  __shared__ float red[2];
  __shared__ float ybuf[128];
  float x = kpre[(size_t)s*128 + tid];
  float v = x;
  #pragma unroll
  for(int o=32;o>0;o>>=1) v += __shfl_down(v,o,64);
  if((tid&63)==0) red[tid>>6]=v;
  __syncthreads();
  float mean = (red[0]+red[1])*(1.f/128.f);
  __syncthreads();
  float dx = x - mean;
  v = dx*dx;
  #pragma unroll
  for(int o=32;o>0;o>>=1) v += __shfl_down(v,o,64);
  if((tid&63)==0) red[tid>>6]=v;
  __syncthreads();
  float var = (red[0]+red[1])*(1.f/128.f);
  float y = dx*rsqrtf(var+1e-5f)*w[tid] + bb[tid];
  ybuf[tid]=y;
  __syncthreads();
  float r;
  if(tid<32){ float c0=fcos[(size_t)s*32+tid], s_=fsin[(size_t)s*32+tid]; r = ybuf[tid]*c0 - ybuf[tid+32]*s_; }
  else if(tid<64){ int i2=tid-32; float c0=fcos[(size_t)s*32+i2], s_=fsin[(size_t)s*32+i2]; r = ybuf[i2]*s_ + ybuf[tid]*c0; }
  else r = y;
  u16 hv=f2bf(r);
  hi[(size_t)s*128+tid]=hv;
  lo[(size_t)s*128+tid]=f2bf(r-bf2f(hv));
}

__global__ void assemble_kv(const float* __restrict__ kvp, const float* __restrict__ kpe,
                            u16* __restrict__ kb, u16* __restrict__ vb){
  int i0 = blockIdx.x*blockDim.x + threadIdx.x;
  int st = gridDim.x*blockDim.x;
  for(int idx=i0; idx<2048*16*192; idx+=st){
    int s = idx/3072; int rrem = idx - s*3072; int hh = rrem/192; int d = rrem - hh*192;
    float val = (d<128) ? kvp[(size_t)s*4096 + hh*256 + d] : kpe[(size_t)s*64 + (d-128)];
    kb[idx] = f2bf(val);
  }
  for(int idx=i0; idx<2048*16*128; idx+=st){
    int s = idx>>11; int rrem = idx & 2047; int hh = rrem>>7; int d = rrem&127;
    vb[idx] = f2bf(kvp[(size_t)s*4096 + hh*256 + 128 + d]);
  }
}

// ---------------- fused indexer scores ----------------
DEV void isc_pass(const u16* Q, const u16* KT, f32x4 (&sc)[2][2], int wr, int wc, int l15, int l16){
  #pragma unroll
  for(int ks=0;ks<4;ks++){
    bf16x8 a[2], b[2];
    #pragma unroll
    for(int m=0;m<2;m++) a[m] = *reinterpret_cast<const bf16x8*>(&Q[(wr*32+m*16+l15)*136 + ks*32 + l16*8]);
    #pragma unroll
    for(int n=0;n<2;n++) b[n] = *reinterpret_cast<const bf16x8*>(&KT[(wc*32+n*16+l15)*136 + ks*32 + l16*8]);
    #pragma unroll
    for(int m=0;m<2;m++)
      #pragma unroll
      for(int n=0;n<2;n++) sc[m][n] = MFMA(a[m], b[n], sc[m][n]);
  }
}

__global__ __launch_bounds__(256,2) void idx_scores(
    const u16* __restrict__ qih, const u16* __restrict__ qil,
    const u16* __restrict__ kih, const u16* __restrict__ kil,
    const float* __restrict__ wts, float* __restrict__ outp)
{
  __shared__ u16 Kh[64*136];
  __shared__ u16 Kl[64*136];
  __shared__ u16 Qb[64*136];
  int bid = blockIdx.x;
  int si=0, t=bid;
  while(t >= si+1){ t -= si+1; si++; }
  int ti = t;
  int s0 = si*64, t0 = ti*64;
  int tid=threadIdx.x, w=tid>>6, l=tid&63;
  int wr=w>>1, wc=w&1, l15=l&15, l16=l>>4;
  #pragma unroll
  for(int i=0;i<4;i++){
    int slot=tid+i*256; int row=slot>>4, part=(slot&15)*8;
    *reinterpret_cast<u32x4*>(&Kh[row*136+part]) = *reinterpret_cast<const u32x4*>(&kih[(size_t)(t0+row)*128 + part]);
    *reinterpret_cast<u32x4*>(&Kl[row*136+part]) = *reinterpret_cast<const u32x4*>(&kil[(size_t)(t0+row)*128 + part]);
  }
  f32x4 accI[2][2];
  #pragma unroll
  for(int m=0;m<2;m++) for(int n=0;n<2;n++) accI[m][n] = f32x4{0.f,0.f,0.f,0.f};
  const float dscale = 0.08838834764831843f; // 1/sqrt(128)
  for(int h=0;h<32;h++){
    __syncthreads();
    #pragma unroll
    for(int i=0;i<4;i++){
      int slot=tid+i*256; int row=slot>>4, part=(slot&15)*8;
      *reinterpret_cast<u32x4*>(&Qb[row*136+part]) = *reinterpret_cast<const u32x4*>(&qih[(size_t)(s0+row)*4096 + h*128 + part]);
    }
    __syncthreads();
    f32x4 sc[2][2];
    #pragma unroll
    for(int m=0;m<2;m++) for(int n=0;n<2;n++) sc[m][n] = f32x4{0.f,0.f,0.f,0.f};
    isc_pass(Qb, Kh, sc, wr, wc, l15, l16);
    isc_pass(Qb, Kl, sc, wr, wc, l15, l16);
    __syncthreads();
    #pragma unroll
    for(int i=0;i<4;i++){
      int slot=tid+i*256; int row=slot>>4, part=(slot&15)*8;
      *reinterpret_cast<u32x4*>(&Qb[row*136+part]) = *reinterpret_cast<const u32x4*>(&qil[(size_t)(s0+row)*4096 + h*128 + part]);
    }
    __syncthreads();
    isc_pass(Qb, Kh, sc, wr, wc, l15, l16);
    #pragma unroll
    for(int m=0;m<2;m++)
      #pragma unroll
      for(int r=0;r<4;r++){
        float wv = wts[(size_t)(s0+wr*32+m*16+l16*4+r)*32 + h]*dscale;
        #pragma unroll
        for(int n=0;n<2;n++) accI[m][n][r] += fmaxf(sc[m][n][r],0.f)*wv;
      }
  }
  #pragma unroll
  for(int m=0;m<2;m++)
    #pragma unroll
    for(int n=0;n<2;n++)
      #pragma unroll
      for(int r=0;r<4;r++)
        outp[(size_t)(s0+wr*32+m*16+l16*4+r)*2048 + t0+wc*32+n*16+l15] = accI[m][n][r];
}

// ---------------- exact top-512 per row -> bitmask ----------------
DEV uint fkey(float f){ union{float f;uint u;} v; v.f=f; return (v.u & 0x80000000u) ? ~v.u : (v.u | 0x80000000u); }

__global__ __launch_bounds__(256) void topk_mask(const float* __restrict__ scores, u64* __restrict__ bits){
  int s = blockIdx.x;
  int n = s+1;
  int tid = threadIdx.x;
  const float* row = scores + (size_t)s*2048;
  if(n <= 512){
    for(int wI=tid; wI<32; wI+=256){
      u64 m=0; int base=wI*64;
      if(base < n){ int cnt=n-base; m = (cnt>=64)? ~0ull : ((1ull<<cnt)-1ull); }
      bits[(size_t)s*32+wI]=m;
    }
    return;
  }
  __shared__ uint hist[256];
  __shared__ uint sh_B, sh_k;
  __shared__ uint wcnt[32];
  uint prefix=0, k=512;
  for(int shift=24; shift>=0; shift-=8){
    hist[tid]=0;
    __syncthreads();
    for(int t2=tid;t2<n;t2+=256){
      uint u = fkey(row[t2]);
      bool ok = (shift==24) || ((u>>(shift+8)) == (prefix>>(shift+8)));
      if(ok) atomicAdd(&hist[(u>>shift)&255u],1u);
    }
    __syncthreads();
    if(tid==0){
      uint c=0;
      for(int b2=255;b2>=0;b2--){
        c += hist[b2];
        if(c>=k){ sh_B=(uint)b2; sh_k = k-(c-hist[b2]); break; }
      }
    }
    __syncthreads();
    prefix |= sh_B<<shift;
    k = sh_k;
    __syncthreads();
  }
  uint thr = prefix;
  if(tid<32) wcnt[tid]=0;
  __syncthreads();
  int nw = (n+63)>>6;
  if(tid < nw){
    int base=tid*64, end = base+64; if(end>n) end=n;
    uint c=0;
    for(int t2=base;t2<end;t2++) if(fkey(row[t2])==thr) c++;
    wcnt[tid]=c;
  }
  __syncthreads();
  if(tid==0){
    uint runv=0;
    for(int i=0;i<32;i++){ uint c=wcnt[i]; wcnt[i]=runv; runv+=c; }
  }
  __syncthreads();
  if(tid<32){
    u64 m=0; int base=tid*64;
    if(base<n){
      uint rank = wcnt[tid];
      int end = base+64; if(end>n) end=n;
      for(int t2=base;t2<end;t2++){
        uint u = fkey(row[t2]);
        if(u>thr) m |= (1ull<<(t2-base));
        else if(u==thr){ if(rank<k) m |= (1ull<<(t2-base)); rank++; }
      }
    }
    bits[(size_t)s*32+tid]=m;
  }
}

// ---------------- flash attention with topk bitmask ----------------
__global__ __launch_bounds__(256,2) void flash_attn(
    const u16* __restrict__ q, const u16* __restrict__ k, const u16* __restrict__ v,
    const u64* __restrict__ bits, u16* __restrict__ o)
{
  __shared__ u16 Ks[64*200];
  __shared__ u16 Vt[128*72];
  __shared__ u16 Pl[128*72];
  int sblk = 15 - (int)blockIdx.x;   // heavy blocks dispatched first
  int h = blockIdx.y;
  int s0 = sblk*128;
  int tid=threadIdx.x, w=tid>>6, l=tid&63;
  int l15=l&15, l16=l>>4;
  const float sscale = 0.07216878364870323f; // 1/sqrt(192)
  bf16x8 qf[2][6];
  #pragma unroll
  for(int m=0;m<2;m++)
    #pragma unroll
    for(int ks=0;ks<6;ks++)
      qf[m][ks] = *reinterpret_cast<const bf16x8*>(&q[((size_t)(s0+w*32+m*16+l15)*16 + h)*192 + ks*32 + l16*8]);
  f32x4 Oa[2][8];
  #pragma unroll
  for(int m=0;m<2;m++) for(int n=0;n<8;n++) Oa[m][n] = f32x4{0.f,0.f,0.f,0.f};
  float mrun[2][4], lrun[2][4];
  #pragma unroll
  for(int m=0;m<2;m++) for(int r=0;r<4;r++){ mrun[m][r]=-__builtin_inff(); lrun[m][r]=0.f; }
  int ntt = 2*sblk+2;
  for(int tt=0;tt<ntt;tt++){
    int t0 = tt*64;
    __syncthreads();
    #pragma unroll
    for(int i=0;i<6;i++){
      int slot = tid + i*256;
      int rowt = slot/24, part=(slot%24)*8;
      *reinterpret_cast<u32x4*>(&Ks[rowt*200+part]) =
        *reinterpret_cast<const u32x4*>(&k[((size_t)(t0+rowt)*16 + h)*192 + part]);
    }
    #pragma unroll
    for(int i=0;i<4;i++){
      int slot = tid + i*256;
      int dv = slot & 127, tg = slot >> 7;
      u16x8 pk;
      #pragma unroll
      for(int j=0;j<8;j++) pk[j] = v[((size_t)(t0+tg*8+j)*16 + h)*128 + dv];
      *reinterpret_cast<u16x8*>(&Vt[dv*72 + tg*8]) = pk;
    }
    __syncthreads();
    f32x4 S[2][4];
    #pragma unroll
    for(int m=0;m<2;m++) for(int n=0;n<4;n++) S[m][n] = f32x4{0.f,0.f,0.f,0.f};
    #pragma unroll
    for(int ks=0;ks<6;ks++){
      bf16x8 b[4];
      #pragma unroll
      for(int n=0;n<4;n++) b[n] = *reinterpret_cast<const bf16x8*>(&Ks[(n*16+l15)*200 + ks*32 + l16*8]);
      #pragma unroll
      for(int m=0;m<2;m++)
        #pragma unroll
        for(int n=0;n<4;n++) S[m][n] = MFMA(qf[m][ks], b[n], S[m][n]);
    }
    #pragma unroll
    for(int m=0;m<2;m++){
      #pragma unroll
      for(int r=0;r<4;r++){
        int srow = s0 + w*32 + m*16 + l16*4 + r;
        u64 wrd = bits[(size_t)srow*32 + (t0>>6)];
        float mx = -__builtin_inff();
        #pragma unroll
        for(int n=0;n<4;n++){
          int tcol = t0 + n*16 + l15;
          int bitp = n*16 + l15;
          bool ok = (tcol <= srow) && ((wrd>>bitp)&1ull);
          float val = ok ? S[m][n][r]*sscale : -__builtin_inff();
          S[m][n][r] = val;
          mx = fmaxf(mx, val);
        }
        #pragma unroll
        for(int off=1;off<16;off<<=1) mx = fmaxf(mx, __shfl_xor(mx, off, 64));
        float mold = mrun[m][r];
        float mnew = fmaxf(mold, mx);
        bool inf0 = (mnew == -__builtin_inff());
        float alpha = inf0 ? 1.f : __expf(mold - mnew);
        float rs = 0.f;
        #pragma unroll
        for(int n=0;n<4;n++){
          float p = inf0 ? 0.f : __expf(S[m][n][r] - mnew);
          S[m][n][r] = p;
          rs += p;
        }
        #pragma unroll
        for(int off=1;off<16;off<<=1) rs += __shfl_xor(rs, off, 64);
        mrun[m][r]=mnew;
        lrun[m][r] = lrun[m][r]*alpha + rs;
        #pragma unroll
        for(int n=0;n<8;n++) Oa[m][n][r] *= alpha;
      }
    }
    // P -> LDS (wave-private rows: no barrier needed; same-wave DS ordering)
    #pragma unroll
    for(int m=0;m<2;m++)
      #pragma unroll
      for(int n=0;n<4;n++)
        #pragma unroll
        for(int r=0;r<4;r++)
          Pl[(w*32+m*16+l16*4+r)*72 + n*16+l15] = f2bf(S[m][n][r]);
    #pragma unroll
    for(int ks=0;ks<2;ks++){
      bf16x8 a[2], bb[8];
      #pragma unroll
      for(int m=0;m<2;m++) a[m] = *reinterpret_cast<const bf16x8*>(&Pl[(w*32+m*16+l15)*72 + ks*32 + l16*8]);
      #pragma unroll
      for(int n=0;n<8;n++) bb[n] = *reinterpret_cast<const bf16x8*>(&Vt[(n*16+l15)*72 + ks*32 + l16*8]);
      #pragma unroll
      for(int m=0;m<2;m++)
        #pragma unroll
        for(int n=0;n<8;n++) Oa[m][n] = MFMA(a[m], bb[n], Oa[m][n]);
    }
  }
  #pragma unroll
  for(int m=0;m<2;m++)
    #pragma unroll
    for(int r=0;r<4;r++){
      int srow = s0 + w*32 + m*16 + l16*4 + r;
      float inv = 1.f/lrun[m][r];
      #pragma unroll
      for(int n=0;n<8;n++)
        o[(size_t)srow*2048 + h*128 + n*16 + l15] = f2bf(Oa[m][n][r]*inv);
    }
}

// ---------------- host ----------------
extern "C" void kernel_launch(void* const* d_in, const int* in_sizes, int n_in,
                              void* d_out, int out_size, void* d_ws, size_t ws_size,
                              hipStream_t stream)
{
  (void)in_sizes; (void)n_in; (void)out_size;
  const float* hs   = (const float*)d_in[0];
  const float* wqa  = (const float*)d_in[1];
  const float* qnw  = (const float*)d_in[2];
  const float* wqbw = (const float*)d_in[3];
  const float* wkva = (const float*)d_in[4];
  const float* kvnw = (const float*)d_in[5];
  const float* wkvb = (const float*)d_in[6];
  const float* wow  = (const float*)d_in[7];
  const float* iwqb = (const float*)d_in[8];
  const float* iwk  = (const float*)d_in[9];
  const float* iknw = (const float*)d_in[10];
  const float* iknb = (const float*)d_in[11];
  const float* iwp  = (const float*)d_in[12];
  const float* fcos = (const float*)d_in[13];
  const float* fsin = (const float*)d_in[14];
  float* outp = (float*)d_out;

  char* base = (char*)d_ws;
  size_t off = 0;
  auto alloc = [&](size_t bytes)->char*{ char* p = base+off; off += (bytes+255)&~(size_t)255; return p; };
  u16* hid_hi = (u16*)alloc(2048ull*2048*2);
  u16* hid_lo = (u16*)alloc(2048ull*2048*2);
  u16* wqa_hi = (u16*)alloc(1536ull*2048*2);
  u16* wqa_lo = (u16*)alloc(1536ull*2048*2);
  u16* wqb_b  = (u16*)alloc(3072ull*1536*2);
  u16* wkva_b = (u16*)alloc(576ull*2048*2);
  u16* wkvb_b = (u16*)alloc(4096ull*512*2);
  u16* wo_b   = (u16*)alloc(2048ull*2048*2);
  u16* iwqb_hi= (u16*)alloc(4096ull*1536*2);
  u16* iwqb_lo= (u16*)alloc(4096ull*1536*2);
  u16* iwk_hi = (u16*)alloc(128ull*2048*2);
  u16* iwk_lo = (u16*)alloc(128ull*2048*2);
  u16* iwp_hi = (u16*)alloc(32ull*2048*2);
  u16* iwp_lo = (u16*)alloc(32ull*2048*2);
  u16* qr_hi  = (u16*)alloc(2048ull*1536*2);
  u16* qr_lo  = (u16*)alloc(2048ull*1536*2);
  u16* kv_b   = (u16*)alloc(2048ull*512*2);
  float* kpe  = (float*)alloc(2048ull*64*4);
  u16* k_b    = (u16*)alloc(2048ull*16*192*2);
  u16* v_b    = (u16*)alloc(2048ull*16*128*2);
  u16* ki_hi  = (u16*)alloc(2048ull*128*2);
  u16* ki_lo  = (u16*)alloc(2048ull*128*2);
  float* wts  = (float*)alloc(2048ull*32*4);
  u64* bits   = (u64*)alloc(2048ull*32*8);
  u16* attn_b = (u16*)alloc(2048ull*2048*2);
  float* reg1 = (float*)alloc(2048ull*4096*4); // qr_pre/q_pre/kv_all/kvp/ki_pre/qi_pre/index_scores (sequential lifetimes)
  if(ws_size < off) return; // loud failure if workspace too small

  // aliases (lifetime-checked)
  u16* q_b    = wqa_hi;   // after wq_a last read
  u16* qi_hi  = hid_hi;   // after hidden last read (wts GEMM)
  u16* qi_lo  = iwqb_hi;  // after idx_wq_b last read (qi GEMM)
  float* qr_pre = reg1;
  float* q_pre  = reg1;
  float* kvall  = reg1;
  float* kvpb   = reg1;
  float* ki_pre = reg1;
  float* qi_pre = reg1;
  float* iscore = reg1;

  auto GEMM = [&](const u16* A,int lda,const u16* B2,int ldb,float* C,int ldc,int M,int N,int K2,float alpha,int accum){
    dim3 g((unsigned)((N+127)/128), (unsigned)((M+127)/128), 1);
    gemm_nt<<<g,256,0,stream>>>(A,lda,B2,ldb,C,ldc,M,N,K2,alpha,accum);
  };

  // converts
  cvt_split_v4<<<1024,256,0,stream>>>(hs, hid_hi, hid_lo, 2048*2048/4);
  cvt_split_v4<<<1024,256,0,stream>>>(wqa, wqa_hi, wqa_lo, 1536*2048/4);
  cvt_split_v4<<<1024,256,0,stream>>>(iwqb, iwqb_hi, iwqb_lo, 4096*1536/4);
  cvt_split_v4<<<256,256,0,stream>>>(iwk, iwk_hi, iwk_lo, 128*2048/4);
  cvt_split_v4<<<64,256,0,stream>>>(iwp, iwp_hi, iwp_lo, 32*2048/4);
  cvt_bf16_v4<<<1024,256,0,stream>>>(wqbw, wqb_b, 3072*1536/4);
  cvt_bf16_v4<<<512,256,0,stream>>>(wkva, wkva_b, 576*2048/4);
  cvt_bf16_v4<<<512,256,0,stream>>>(wkvb, wkvb_b, 4096*512/4);
  cvt_bf16_v4<<<1024,256,0,stream>>>(wow, wo_b, 2048*2048/4);

  // qr = rmsnorm(hidden @ wq_a^T)  [split precision]
  GEMM(hid_hi,2048, wqa_hi,2048, qr_pre,1536, 2048,1536,2048, 1.f, 0);
  GEMM(hid_hi,2048, wqa_lo,2048, qr_pre,1536, 2048,1536,2048, 1.f, 1);
  GEMM(hid_lo,2048, wqa_hi,2048, qr_pre,1536, 2048,1536,2048, 1.f, 1);
  rmsnorm_qr_split<<<2048,256,0,stream>>>(qr_pre, qnw, qr_hi, qr_lo);

  // q path
  GEMM(qr_hi,1536, wqb_b,1536, q_pre,3072, 2048,3072,1536, 1.f, 0);
  rope_q_cvt<<<2048,256,0,stream>>>(q_pre, fcos, fsin, q_b);

  // kv path
  GEMM(hid_hi,2048, wkva_b,2048, kvall,576, 2048,576,2048, 1.f, 0);
  kv_norm_rope<<<2048,256,0,stream>>>(kvall, kvnw, fcos, fsin, kv_b, kpe);
  GEMM(kv_b,512, wkvb_b,512, kvpb,4096, 2048,4096,512, 1.f, 0);
  assemble_kv<<<2048,256,0,stream>>>(kvpb, kpe, k_b, v_b);

  // indexer: ki
  GEMM(hid_hi,2048, iwk_hi,2048, ki_pre,128, 2048,128,2048, 1.f, 0);
  GEMM(hid_hi,2048, iwk_lo,2048, ki_pre,128, 2048,128,2048, 1.f, 1);
  GEMM(hid_lo,2048, iwk_hi,2048, ki_pre,128, 2048,128,2048, 1.f, 1);
  ki_ln_rope_split<<<2048,128,0,stream>>>(ki_pre, iknw, iknb, fcos, fsin, ki_hi, ki_lo);

  // indexer: wts (fold HI^-0.5)
  const float ascale = 0.17677669529663687f;
  GEMM(hid_hi,2048, iwp_hi,2048, wts,32, 2048,32,2048, ascale, 0);
  GEMM(hid_hi,2048, iwp_lo,2048, wts,32, 2048,32,2048, ascale, 1);
  GEMM(hid_lo,2048, iwp_hi,2048, wts,32, 2048,32,2048, ascale, 1);

  // indexer: qi  (hidden dead now -> qi_hi over hidden; iwqb dead after these -> qi_lo over iwqb)
  GEMM(qr_hi,1536, iwqb_hi,1536, qi_pre,4096, 2048,4096,1536, 1.f, 0);
  GEMM(qr_hi,1536, iwqb_lo,1536, qi_pre,4096, 2048,4096,1536, 1.f, 1);
  GEMM(qr_lo,1536, iwqb_hi,1536, qi_pre,4096, 2048,4096,1536, 1.f, 1);
  qi_rope_split<<<2048,256,0,stream>>>(qi_pre, fcos, fsin, qi_hi, qi_lo);

  // fused index scores (causal 64x64 tiles), exact top-512 mask
  idx_scores<<<528,256,0,stream>>>(qi_hi, qi_lo, ki_hi, ki_lo, wts, iscore);
  topk_mask<<<2048,256,0,stream>>>(iscore, bits);

  // attention + output projection
  flash_attn<<<dim3(16,16),256,0,stream>>>(q_b, k_b, v_b, bits, attn_b);
  GEMM(attn_b,2048, wo_b,2048, outp,2048, 2048,2048,2048, 1.f, 0);
}

// Round 3
// 726.378 us; speedup vs baseline: 1.6339x; 1.6339x over previous
//
#include <hip/hip_runtime.h>
#include <stdint.h>

typedef unsigned int uint;
typedef unsigned short u16;
typedef unsigned long long u64;

typedef float  f32x4 __attribute__((ext_vector_type(4)));
typedef uint   u32x4 __attribute__((ext_vector_type(4)));
typedef u16    u16x4 __attribute__((ext_vector_type(4)));
typedef u16    u16x8 __attribute__((ext_vector_type(8)));
typedef __bf16 bf16x8 __attribute__((ext_vector_type(8)));

#define DEV static __device__ __forceinline__
#define MFMA(a,b,c) __builtin_amdgcn_mfma_f32_16x16x32_bf16((a),(b),(c),0,0,0)

DEV u16 f2bf(float x){ union{float f;uint u;} v; v.f=x; return (u16)((v.u + 0x7fffu + ((v.u>>16)&1u))>>16); }
DEV float bf2f(u16 b){ union{uint u;float f;} v; v.u=((uint)b)<<16; return v.f; }

// ---------------- converts ----------------
__global__ void cvt_bf16_v4(const float* __restrict__ in, u16* __restrict__ out, int n4){
  int i = blockIdx.x*blockDim.x + threadIdx.x;
  int st = gridDim.x*blockDim.x;
  for(; i<n4; i+=st){
    f32x4 x = reinterpret_cast<const f32x4*>(in)[i];
    u16x4 y;
    #pragma unroll
    for(int j=0;j<4;j++) y[j] = f2bf(x[j]);
    reinterpret_cast<u16x4*>(out)[i] = y;
  }
}

__global__ void cvt_split_v4(const float* __restrict__ in, u16* __restrict__ hi, u16* __restrict__ lo, int n4){
  int i = blockIdx.x*blockDim.x + threadIdx.x;
  int st = gridDim.x*blockDim.x;
  for(; i<n4; i+=st){
    f32x4 x = reinterpret_cast<const f32x4*>(in)[i];
    u16x4 h, l;
    #pragma unroll
    for(int j=0;j<4;j++){
      u16 hb = f2bf(x[j]); h[j]=hb;
      l[j] = f2bf(x[j] - bf2f(hb));
    }
    reinterpret_cast<u16x4*>(hi)[i] = h;
    reinterpret_cast<u16x4*>(lo)[i] = l;
  }
}

// ---------------- GEMM (global_load_lds staging, m97 structure) ----------------
// C[M,N] = A[M,K] * B[N,K]^T ; SPLIT=1: A,B given as hi+lo, 3 MFMA passes (hh+hl+lh)
DEV void stage128x32(const u16* __restrict__ gbase, int ld, int row0, int maxrow, int k0, u16* lds){
  int tid = threadIdx.x, w = tid>>6, l = tid&63;
  #pragma unroll
  for(int j=0;j<2;j++){
    int seg = w + j*4;
    int row = seg*16 + (l>>2);
    int gr = row0 + row; if(gr > maxrow) gr = maxrow;
    const u16* g = gbase + (size_t)gr*ld + k0 + (l&3)*8;
    __builtin_amdgcn_global_load_lds(
        (const __attribute__((address_space(1))) void*)g,
        (__attribute__((address_space(3))) void*)(lds + seg*512), 16, 0, 0);
  }
}

template<int SPLIT>
__global__ __launch_bounds__(256,2) void gemm_glds(
    const u16* __restrict__ Ah, const u16* __restrict__ Al, int lda,
    const u16* __restrict__ Bh, const u16* __restrict__ Bl, int ldb,
    float* __restrict__ C, int ldc, int M, int N, int K)
{
  __shared__ u16 sAh[128*32];
  __shared__ u16 sBh[128*32];
  __shared__ u16 sAl[SPLIT?128*32:8];
  __shared__ u16 sBl[SPLIT?128*32:8];
  const int tid = threadIdx.x;
  const int w = tid>>6, l = tid&63;
  const int wr = w>>1, wc = w&1;
  const int l15 = l&15, l16 = l>>4;

  // XCD-aware bijective block swizzle (m204)
  int gx = gridDim.x;
  int nwg = gx*gridDim.y;
  int orig = blockIdx.x + gx*blockIdx.y;
  int qq = nwg>>3, rr = nwg&7, xc = orig&7, oo = orig>>3;
  int wg = (xc<rr ? xc*(qq+1) : rr*(qq+1)+(xc-rr)*qq) + oo;
  int m0 = (wg/gx)*128, n0 = (wg%gx)*128;

  int kz = K/(int)gridDim.z;
  int kbeg = blockIdx.z*kz;

  f32x4 acc[4][4];
  #pragma unroll
  for(int m=0;m<4;m++)
    #pragma unroll
    for(int n=0;n<4;n++) acc[m][n] = f32x4{0.f,0.f,0.f,0.f};

  for(int k0=kbeg; k0<kbeg+kz; k0+=32){
    __syncthreads();
    stage128x32(Ah, lda, m0, M-1, k0, sAh);
    stage128x32(Bh, ldb, n0, N-1, k0, sBh);
    if(SPLIT){
      stage128x32(Al, lda, m0, M-1, k0, sAl);
      stage128x32(Bl, ldb, n0, N-1, k0, sBl);
    }
    asm volatile("s_waitcnt vmcnt(0)" ::: "memory");
    __syncthreads();
    bf16x8 ah[4], bh[4];
    #pragma unroll
    for(int m=0;m<4;m++) ah[m] = *reinterpret_cast<const bf16x8*>(&sAh[(wr*64+m*16+l15)*32 + l16*8]);
    #pragma unroll
    for(int n=0;n<4;n++) bh[n] = *reinterpret_cast<const bf16x8*>(&sBh[(wc*64+n*16+l15)*32 + l16*8]);
    #pragma unroll
    for(int m=0;m<4;m++)
      #pragma unroll
      for(int n=0;n<4;n++) acc[m][n] = MFMA(ah[m], bh[n], acc[m][n]);
    if(SPLIT){
      bf16x8 t[4];
      #pragma unroll
      for(int n=0;n<4;n++) t[n] = *reinterpret_cast<const bf16x8*>(&sBl[(wc*64+n*16+l15)*32 + l16*8]);
      #pragma unroll
      for(int m=0;m<4;m++)
        #pragma unroll
        for(int n=0;n<4;n++) acc[m][n] = MFMA(ah[m], t[n], acc[m][n]);
      #pragma unroll
      for(int m=0;m<4;m++) t[m] = *reinterpret_cast<const bf16x8*>(&sAl[(wr*64+m*16+l15)*32 + l16*8]);
      #pragma unroll
      for(int m=0;m<4;m++)
        #pragma unroll
        for(int n=0;n<4;n++) acc[m][n] = MFMA(t[m], bh[n], acc[m][n]);
    }
  }
  float* Cp = C + (size_t)blockIdx.z*M*ldc;
  #pragma unroll
  for(int m=0;m<4;m++){
    int row = m0 + wr*64 + m*16 + l16*4;
    #pragma unroll
    for(int n=0;n<4;n++){
      int col = n0 + wc*64 + n*16 + l15;
      if(col < N){
        #pragma unroll
        for(int r=0;r<4;r++){
          int rrow = row + r;
          if(rrow < M) Cp[(size_t)rrow*ldc + col] = acc[m][n][r];
        }
      }
    }
  }
}

__global__ void ksum(const float* __restrict__ P, float* __restrict__ C, int n4, int z, size_t plane4){
  int i = blockIdx.x*blockDim.x + threadIdx.x;
  int st = gridDim.x*blockDim.x;
  for(; i<n4; i+=st){
    f32x4 s = reinterpret_cast<const f32x4*>(P)[i];
    for(int c=1;c<z;c++) s += reinterpret_cast<const f32x4*>(P)[(size_t)i + (size_t)c*plane4];
    reinterpret_cast<f32x4*>(C)[i] = s;
  }
}

// ---------------- norms / rope ----------------
__global__ __launch_bounds__(256) void rmsnorm_qr_split(
    const float* __restrict__ in, const float* __restrict__ w,
    u16* __restrict__ hi, u16* __restrict__ lo)
{
  int s = blockIdx.x, tid = threadIdx.x;
  __shared__ float red[4];
  const float* x = in + (size_t)s*1536;
  float xv[6]; float ss=0.f;
  #pragma unroll
  for(int i=0;i<6;i++){ xv[i] = x[tid + i*256]; ss += xv[i]*xv[i]; }
  #pragma unroll
  for(int o=32;o>0;o>>=1) ss += __shfl_down(ss,o,64);
  if((tid&63)==0) red[tid>>6]=ss;
  __syncthreads();
  float total = red[0]+red[1]+red[2]+red[3];
  float scale = rsqrtf(total*(1.0f/1536.0f) + 1e-6f);
  #pragma unroll
  for(int i=0;i<6;i++){
    int c = tid + i*256;
    float vv = xv[i]*scale*w[c];
    u16 hv = f2bf(vv);
    hi[(size_t)s*1536+c]=hv;
    lo[(size_t)s*1536+c]=f2bf(vv - bf2f(hv));
  }
}

__global__ __launch_bounds__(256) void kv_norm_rope(
    const float* __restrict__ kvall, const float* __restrict__ w,
    const float* __restrict__ fcos, const float* __restrict__ fsin,
    u16* __restrict__ kvb, float* __restrict__ kpe)
{
  int s = blockIdx.x, tid = threadIdx.x;
  __shared__ float red[4];
  const float* x = kvall + (size_t)s*576;
  float xv[2]; float ss=0.f;
  #pragma unroll
  for(int i=0;i<2;i++){ xv[i]=x[tid+i*256]; ss+=xv[i]*xv[i]; }
  #pragma unroll
  for(int o=32;o>0;o>>=1) ss += __shfl_down(ss,o,64);
  if((tid&63)==0) red[tid>>6]=ss;
  __syncthreads();
  float total = red[0]+red[1]+red[2]+red[3];
  float scale = rsqrtf(total*(1.0f/512.0f)+1e-6f);
  #pragma unroll
  for(int i=0;i<2;i++){ int c=tid+i*256; kvb[(size_t)s*512+c]=f2bf(xv[i]*scale*w[c]); }
  if(tid<32){
    float c0=fcos[(size_t)s*32+tid], s_=fsin[(size_t)s*32+tid];
    float x0=x[512+2*tid], x1=x[513+2*tid];
    kpe[(size_t)s*64+2*tid]   = x0*c0 - x1*s_;
    kpe[(size_t)s*64+2*tid+1] = x0*s_ + x1*c0;
  }
}

__global__ __launch_bounds__(256) void rope_q_cvt(const float* __restrict__ qpre,
    const float* __restrict__ fcos, const float* __restrict__ fsin, u16* __restrict__ qb)
{
  int s = blockIdx.x;
  const float* rowp = qpre + (size_t)s*3072;
  u16* op = qb + (size_t)s*3072;
  for(int idx=threadIdx.x; idx<3072; idx+=256){
    int hh = idx/192, d = idx - hh*192;
    float vv;
    if(d < 128) vv = rowp[hh*192 + d];
    else{
      int i2 = (d-128)>>1;
      float c0 = fcos[(size_t)s*32+i2], s_ = fsin[(size_t)s*32+i2];
      float x0 = rowp[hh*192 + 128 + 2*i2], x1 = rowp[hh*192 + 129 + 2*i2];
      vv = ((d&1)==0) ? (x0*c0 - x1*s_) : (x0*s_ + x1*c0);
    }
    op[idx] = f2bf(vv);
  }
}

__global__ __launch_bounds__(256) void qi_rope_split(const float* __restrict__ qpre,
    const float* __restrict__ fcos, const float* __restrict__ fsin,
    u16* __restrict__ hi, u16* __restrict__ lo)
{
  int s = blockIdx.x;
  const float* rowp = qpre + (size_t)s*4096;
  for(int idx=threadIdx.x; idx<4096; idx+=256){
    int hh = idx>>7, d = idx&127;
    const float* hb = rowp + (hh<<7);
    float vv;
    if(d<32){ float c0=fcos[(size_t)s*32+d], s_=fsin[(size_t)s*32+d]; vv = hb[d]*c0 - hb[d+32]*s_; }
    else if(d<64){ int i2=d-32; float c0=fcos[(size_t)s*32+i2], s_=fsin[(size_t)s*32+i2]; vv = hb[i2]*s_ + hb[d]*c0; }
    else vv = hb[d];
    u16 hv = f2bf(vv);
    hi[(size_t)s*4096+idx]=hv;
    lo[(size_t)s*4096+idx]=f2bf(vv - bf2f(hv));
  }
}

__global__ __launch_bounds__(128) void ki_ln_rope_split(
    const float* __restrict__ kpre, const float* __restrict__ w, const float* __restrict__ bb,
    const float* __restrict__ fcos, const float* __restrict__ fsin,
    u16* __restrict__ hi, u16* __restrict__ lo)
{
  int s = blockIdx.x, tid = threadIdx.x;
  __shared__ float red[2];
  __shared__ float ybuf[128];
  float x = kpre[(size_t)s*160 + tid];
  float v = x;
  #pragma unroll
  for(int o=32;o>0;o>>=1) v += __shfl_down(v,o,64);
  if((tid&63)==0) red[tid>>6]=v;
  __syncthreads();
  float mean = (red[0]+red[1])*(1.f/128.f);
  __syncthreads();
  float dx = x - mean;
  v = dx*dx;
  #pragma unroll
  for(int o=32;o>0;o>>=1) v += __shfl_down(v,o,64);
  if((tid&63)==0) red[tid>>6]=v;
  __syncthreads();
  float var = (red[0]+red[1])*(1.f/128.f);
  float y = dx*rsqrtf(var+1e-5f)*w[tid] + bb[tid];
  ybuf[tid]=y;
  __syncthreads();
  float r;
  if(tid<32){ float c0=fcos[(size_t)s*32+tid], s_=fsin[(size_t)s*32+tid]; r = ybuf[tid]*c0 - ybuf[tid+32]*s_; }
  else if(tid<64){ int i2=tid-32; float c0=fcos[(size_t)s*32+i2], s_=fsin[(size_t)s*32+i2]; r = ybuf[i2]*s_ + ybuf[tid]*c0; }
  else r = y;
  u16 hv=f2bf(r);
  hi[(size_t)s*128+tid]=hv;
  lo[(size_t)s*128+tid]=f2bf(r-bf2f(hv));
}

__global__ void assemble_kv(const float* __restrict__ kvp, const float* __restrict__ kpe,
                            u16* __restrict__ kb, u16* __restrict__ vb){
  int i0 = blockIdx.x*blockDim.x + threadIdx.x;
  int st = gridDim.x*blockDim.x;
  for(int idx=i0; idx<2048*16*192; idx+=st){
    int s = idx/3072; int rrem = idx - s*3072; int hh = rrem/192; int d = rrem - hh*192;
    float val = (d<128) ? kvp[(size_t)s*4096 + hh*256 + d] : kpe[(size_t)s*64 + (d-128)];
    kb[idx] = f2bf(val);
  }
  for(int idx=i0; idx<2048*16*128; idx+=st){
    int s = idx>>11; int rrem = idx & 2047; int hh = rrem>>7; int d = rrem&127;
    vb[idx] = f2bf(kvp[(size_t)s*4096 + hh*256 + 128 + d]);
  }
}

// ---------------- fused indexer scores ----------------
DEV void isc_pass(const u16* Q, const u16* KT, f32x4 (&sc)[2][2], int wr, int wc, int l15, int l16){
  #pragma unroll
  for(int ks=0;ks<4;ks++){
    bf16x8 a[2], b[2];
    #pragma unroll
    for(int m=0;m<2;m++) a[m] = *reinterpret_cast<const bf16x8*>(&Q[(wr*32+m*16+l15)*136 + ks*32 + l16*8]);
    #pragma unroll
    for(int n=0;n<2;n++) b[n] = *reinterpret_cast<const bf16x8*>(&KT[(wc*32+n*16+l15)*136 + ks*32 + l16*8]);
    #pragma unroll
    for(int m=0;m<2;m++)
      #pragma unroll
      for(int n=0;n<2;n++) sc[m][n] = MFMA(a[m], b[n], sc[m][n]);
  }
}

__global__ __launch_bounds__(256,2) void idx_scores(
    const u16* __restrict__ qih, const u16* __restrict__ qil,
    const u16* __restrict__ kih, const u16* __restrict__ kil,
    const float* __restrict__ wts, float* __restrict__ outp)
{
  __shared__ u16 Kh[64*136];
  __shared__ u16 Kl[64*136];
  __shared__ u16 Qb[64*136];
  int bid = blockIdx.x;
  int si=0, t=bid;
  while(t >= si+1){ t -= si+1; si++; }
  int ti = t;
  int s0 = si*64, t0 = ti*64;
  int tid=threadIdx.x, w=tid>>6, l=tid&63;
  int wr=w>>1, wc=w&1, l15=l&15, l16=l>>4;
  #pragma unroll
  for(int i=0;i<4;i++){
    int slot=tid+i*256; int row=slot>>4, part=(slot&15)*8;
    *reinterpret_cast<u32x4*>(&Kh[row*136+part]) = *reinterpret_cast<const u32x4*>(&kih[(size_t)(t0+row)*128 + part]);
    *reinterpret_cast<u32x4*>(&Kl[row*136+part]) = *reinterpret_cast<const u32x4*>(&kil[(size_t)(t0+row)*128 + part]);
  }
  f32x4 accI[2][2];
  #pragma unroll
  for(int m=0;m<2;m++) for(int n=0;n<2;n++) accI[m][n] = f32x4{0.f,0.f,0.f,0.f};
  const float cscale = 0.015625f; // HI^-0.5 * DI^-0.5 = 1/64
  for(int h=0;h<32;h++){
    __syncthreads();
    #pragma unroll
    for(int i=0;i<4;i++){
      int slot=tid+i*256; int row=slot>>4, part=(slot&15)*8;
      *reinterpret_cast<u32x4*>(&Qb[row*136+part]) = *reinterpret_cast<const u32x4*>(&qih[(size_t)(s0+row)*4096 + h*128 + part]);
    }
    __syncthreads();
    f32x4 sc[2][2];
    #pragma unroll
    for(int m=0;m<2;m++) for(int n=0;n<2;n++) sc[m][n] = f32x4{0.f,0.f,0.f,0.f};
    isc_pass(Qb, Kh, sc, wr, wc, l15, l16);
    isc_pass(Qb, Kl, sc, wr, wc, l15, l16);
    __syncthreads();
    #pragma unroll
    for(int i=0;i<4;i++){
      int slot=tid+i*256; int row=slot>>4, part=(slot&15)*8;
      *reinterpret_cast<u32x4*>(&Qb[row*136+part]) = *reinterpret_cast<const u32x4*>(&qil[(size_t)(s0+row)*4096 + h*128 + part]);
    }
    __syncthreads();
    isc_pass(Qb, Kh, sc, wr, wc, l15, l16);
    #pragma unroll
    for(int m=0;m<2;m++)
      #pragma unroll
      for(int r=0;r<4;r++){
        float wv = wts[(size_t)(s0+wr*32+m*16+l16*4+r)*160 + 128 + h]*cscale;
        #pragma unroll
        for(int n=0;n<2;n++) accI[m][n][r] += fmaxf(sc[m][n][r],0.f)*wv;
      }
  }
  #pragma unroll
  for(int m=0;m<2;m++)
    #pragma unroll
    for(int n=0;n<2;n++)
      #pragma unroll
      for(int r=0;r<4;r++)
        outp[(size_t)(s0+wr*32+m*16+l16*4+r)*2048 + t0+wc*32+n*16+l15] = accI[m][n][r];
}

// ---------------- exact top-512 per row -> bitmask ----------------
DEV uint fkey(float f){ union{float f;uint u;} v; v.f=f; return (v.u & 0x80000000u) ? ~v.u : (v.u | 0x80000000u); }

__global__ __launch_bounds__(256) void topk_mask(const float* __restrict__ scores, u64* __restrict__ bits){
  int s = blockIdx.x;
  int n = s+1;
  int tid = threadIdx.x;
  const float* row = scores + (size_t)s*2048;
  if(n <= 512){
    for(int wI=tid; wI<32; wI+=256){
      u64 m=0; int base=wI*64;
      if(base < n){ int cnt=n-base; m = (cnt>=64)? ~0ull : ((1ull<<cnt)-1ull); }
      bits[(size_t)s*32+wI]=m;
    }
    return;
  }
  __shared__ uint hist[256];
  __shared__ uint sh_B, sh_k;
  __shared__ uint wcnt[32];
  uint prefix=0, k=512;
  for(int shift=24; shift>=0; shift-=8){
    hist[tid]=0;
    __syncthreads();
    for(int t2=tid;t2<n;t2+=256){
      uint u = fkey(row[t2]);
      bool ok = (shift==24) || ((u>>(shift+8)) == (prefix>>(shift+8)));
      if(ok) atomicAdd(&hist[(u>>shift)&255u],1u);
    }
    __syncthreads();
    if(tid==0){
      uint c=0;
      for(int b2=255;b2>=0;b2--){
        c += hist[b2];
        if(c>=k){ sh_B=(uint)b2; sh_k = k-(c-hist[b2]); break; }
      }
    }
    __syncthreads();
    prefix |= sh_B<<shift;
    k = sh_k;
    __syncthreads();
  }
  uint thr = prefix;
  if(tid<32) wcnt[tid]=0;
  __syncthreads();
  int nw = (n+63)>>6;
  if(tid < nw){
    int base=tid*64, end = base+64; if(end>n) end=n;
    uint c=0;
    for(int t2=base;t2<end;t2++) if(fkey(row[t2])==thr) c++;
    wcnt[tid]=c;
  }
  __syncthreads();
  if(tid==0){
    uint runv=0;
    for(int i=0;i<32;i++){ uint c=wcnt[i]; wcnt[i]=runv; runv+=c; }
  }
  __syncthreads();
  if(tid<32){
    u64 m=0; int base=tid*64;
    if(base<n){
      uint rank = wcnt[tid];
      int end = base+64; if(end>n) end=n;
      for(int t2=base;t2<end;t2++){
        uint u = fkey(row[t2]);
        if(u>thr) m |= (1ull<<(t2-base));
        else if(u==thr){ if(rank<k) m |= (1ull<<(t2-base)); rank++; }
      }
    }
    bits[(size_t)s*32+tid]=m;
  }
}

// ---------------- flash attention, split-T (partial O + combine) ----------------
__global__ __launch_bounds__(256,2) void flash_attn(
    const u16* __restrict__ q, const u16* __restrict__ k, const u16* __restrict__ v,
    const u64* __restrict__ bits, u16* __restrict__ o,
    u16* __restrict__ Opart, float* __restrict__ ml)
{
  __shared__ u16 Ks[64*200];
  __shared__ u16 Vt[128*72];
  __shared__ u16 Pl[128*72];
  int h = blockIdx.y;
  int pp = blockIdx.x;
  int sblk=0, chunk=0;
  for(int i=0;i<16;i++){ int ncc=(i>>2)+1; if(pp<ncc){ sblk=i; chunk=pp; break; } pp-=ncc; }
  int nc = (sblk>>2)+1;
  int s0 = sblk*128;
  int tid=threadIdx.x, w=tid>>6, l=tid&63;
  int l15=l&15, l16=l>>4;
  const float sscale = 0.07216878364870323f; // 1/sqrt(192)
  bf16x8 qf[2][6];
  #pragma unroll
  for(int m=0;m<2;m++)
    #pragma unroll
    for(int ks=0;ks<6;ks++)
      qf[m][ks] = *reinterpret_cast<const bf16x8*>(&q[((size_t)(s0+w*32+m*16+l15)*16 + h)*192 + ks*32 + l16*8]);
  f32x4 Oa[2][8];
  #pragma unroll
  for(int m=0;m<2;m++) for(int n=0;n<8;n++) Oa[m][n] = f32x4{0.f,0.f,0.f,0.f};
  float mrun[2][4], lrun[2][4];
  #pragma unroll
  for(int m=0;m<2;m++) for(int r=0;r<4;r++){ mrun[m][r]=-__builtin_inff(); lrun[m][r]=0.f; }
  int tt0 = chunk*8;
  int tt1 = chunk*8+8; { int lim = 2*sblk+2; if(tt1>lim) tt1=lim; }
  for(int tt=tt0; tt<tt1; tt++){
    int t0 = tt*64;
    __syncthreads();
    #pragma unroll
    for(int i=0;i<6;i++){
      int slot = tid + i*256;
      int rowt = slot/24, part=(slot%24)*8;
      *reinterpret_cast<u32x4*>(&Ks[rowt*200+part]) =
        *reinterpret_cast<const u32x4*>(&k[((size_t)(t0+rowt)*16 + h)*192 + part]);
    }
    #pragma unroll
    for(int i=0;i<4;i++){
      int slot = tid + i*256;
      int dv = slot & 127, tg = slot >> 7;
      u16x8 pk;
      #pragma unroll
      for(int j=0;j<8;j++) pk[j] = v[((size_t)(t0+tg*8+j)*16 + h)*128 + dv];
      *reinterpret_cast<u16x8*>(&Vt[dv*72 + tg*8]) = pk;
    }
    __syncthreads();
    f32x4 S[2][4];
    #pragma unroll
    for(int m=0;m<2;m++) for(int n=0;n<4;n++) S[m][n] = f32x4{0.f,0.f,0.f,0.f};
    #pragma unroll
    for(int ks=0;ks<6;ks++){
      bf16x8 b[4];
      #pragma unroll
      for(int n=0;n<4;n++) b[n] = *reinterpret_cast<const bf16x8*>(&Ks[(n*16+l15)*200 + ks*32 + l16*8]);
      #pragma unroll
      for(int m=0;m<2;m++)
        #pragma unroll
        for(int n=0;n<4;n++) S[m][n] = MFMA(qf[m][ks], b[n], S[m][n]);
    }
    #pragma unroll
    for(int m=0;m<2;m++){
      #pragma unroll
      for(int r=0;r<4;r++){
        int srow = s0 + w*32 + m*16 + l16*4 + r;
        u64 wrd = bits[(size_t)srow*32 + (t0>>6)];
        float mx = -__builtin_inff();
        #pragma unroll
        for(int n=0;n<4;n++){
          int tcol = t0 + n*16 + l15;
          int bitp = n*16 + l15;
          bool ok = (tcol <= srow) && ((wrd>>bitp)&1ull);
          float val = ok ? S[m][n][r]*sscale : -__builtin_inff();
          S[m][n][r] = val;
          mx = fmaxf(mx, val);
        }
        #pragma unroll
        for(int off=1;off<16;off<<=1) mx = fmaxf(mx, __shfl_xor(mx, off, 64));
        float mold = mrun[m][r];
        float mnew = fmaxf(mold, mx);
        bool inf0 = (mnew == -__builtin_inff());
        float alpha = inf0 ? 1.f : __expf(mold - mnew);
        float rs = 0.f;
        #pragma unroll
        for(int n=0;n<4;n++){
          float p = inf0 ? 0.f : __expf(S[m][n][r] - mnew);
          S[m][n][r] = p;
          rs += p;
        }
        #pragma unroll
        for(int off=1;off<16;off<<=1) rs += __shfl_xor(rs, off, 64);
        mrun[m][r]=mnew;
        lrun[m][r] = lrun[m][r]*alpha + rs;
        #pragma unroll
        for(int n=0;n<8;n++) Oa[m][n][r] *= alpha;
      }
    }
    #pragma unroll
    for(int m=0;m<2;m++)
      #pragma unroll
      for(int n=0;n<4;n++)
        #pragma unroll
        for(int r=0;r<4;r++)
          Pl[(w*32+m*16+l16*4+r)*72 + n*16+l15] = f2bf(S[m][n][r]);
    #pragma unroll
    for(int ks=0;ks<2;ks++){
      bf16x8 a[2], bb[8];
      #pragma unroll
      for(int m=0;m<2;m++) a[m] = *reinterpret_cast<const bf16x8*>(&Pl[(w*32+m*16+l15)*72 + ks*32 + l16*8]);
      #pragma unroll
      for(int n=0;n<8;n++) bb[n] = *reinterpret_cast<const bf16x8*>(&Vt[(n*16+l15)*72 + ks*32 + l16*8]);
      #pragma unroll
      for(int m=0;m<2;m++)
        #pragma unroll
        for(int n=0;n<8;n++) Oa[m][n] = MFMA(a[m], bb[n], Oa[m][n]);
    }
  }
  if(nc == 1){
    #pragma unroll
    for(int m=0;m<2;m++)
      #pragma unroll
      for(int r=0;r<4;r++){
        int srow = s0 + w*32 + m*16 + l16*4 + r;
        float inv = 1.f/lrun[m][r];
        #pragma unroll
        for(int n=0;n<8;n++)
          o[(size_t)srow*2048 + h*128 + n*16 + l15] = f2bf(Oa[m][n][r]*inv);
      }
  } else {
    int part = (h*16+sblk)*4 + chunk;
    u16* Op = Opart + (size_t)part*16384;
    #pragma unroll
    for(int m=0;m<2;m++)
      #pragma unroll
      for(int r=0;r<4;r++){
        int rit = w*32 + m*16 + l16*4 + r;
        #pragma unroll
        for(int n=0;n<8;n++)
          Op[rit*128 + n*16 + l15] = f2bf(Oa[m][n][r]);
        if(l15==0){
          ml[(size_t)part*256 + rit*2]   = mrun[m][r];
          ml[(size_t)part*256 + rit*2+1] = lrun[m][r];
        }
      }
  }
}

__global__ __launch_bounds__(256) void flash_combine(
    const u16* __restrict__ Opart, const float* __restrict__ ml, u16* __restrict__ o)
{
  int b = blockIdx.x;            // h*12 + (sblk-4)
  int h = b/12, sblk = 4 + (b%12);
  int nc = (sblk>>2)+1;
  int tid = threadIdx.x;
  int r = tid>>1, dh = (tid&1)*64;
  int s0 = sblk*128;
  int pbase = (h*16+sblk)*4;
  float m[4], l[4], wgt[4];
  float M = -__builtin_inff();
  for(int c=0;c<nc;c++){
    m[c] = ml[(size_t)(pbase+c)*256 + r*2];
    l[c] = ml[(size_t)(pbase+c)*256 + r*2 + 1];
    if(l[c] > 0.f) M = fmaxf(M, m[c]);
  }
  float L = 0.f;
  for(int c=0;c<nc;c++){
    wgt[c] = (l[c] > 0.f) ? __expf(m[c]-M) : 0.f;
    L += l[c]*wgt[c];
  }
  float inv = 1.f/L;
  for(int dd=0; dd<64; dd+=8){
    float accv[8];
    #pragma unroll
    for(int j=0;j<8;j++) accv[j]=0.f;
    for(int c=0;c<nc;c++){
      u16x8 pv = *reinterpret_cast<const u16x8*>(&Opart[(size_t)(pbase+c)*16384 + r*128 + dh + dd]);
      #pragma unroll
      for(int j=0;j<8;j++) accv[j] += wgt[c]*bf2f(pv[j]);
    }
    u16x8 ov;
    #pragma unroll
    for(int j=0;j<8;j++) ov[j] = f2bf(accv[j]*inv);
    *reinterpret_cast<u16x8*>(&o[(size_t)(s0+r)*2048 + h*128 + dh + dd]) = ov;
  }
}

// ---------------- host ----------------
extern "C" void kernel_launch(void* const* d_in, const int* in_sizes, int n_in,
                              void* d_out, int out_size, void* d_ws, size_t ws_size,
                              hipStream_t stream)
{
  (void)in_sizes; (void)n_in; (void)out_size;
  const float* hs   = (const float*)d_in[0];
  const float* wqa  = (const float*)d_in[1];
  const float* qnw  = (const float*)d_in[2];
  const float* wqbw = (const float*)d_in[3];
  const float* wkva = (const float*)d_in[4];
  const float* kvnw = (const float*)d_in[5];
  const float* wkvb = (const float*)d_in[6];
  const float* wow  = (const float*)d_in[7];
  const float* iwqb = (const float*)d_in[8];
  const float* iwk  = (const float*)d_in[9];
  const float* iknw = (const float*)d_in[10];
  const float* iknb = (const float*)d_in[11];
  const float* iwp  = (const float*)d_in[12];
  const float* fcos = (const float*)d_in[13];
  const float* fsin = (const float*)d_in[14];
  float* outp = (float*)d_out;

  char* base = (char*)d_ws;
  size_t off = 0;
  auto alloc = [&](size_t bytes)->char*{ char* p = base+off; off += (bytes+255)&~(size_t)255; return p; };
  u16* hid_hi = (u16*)alloc(2048ull*2048*2);
  u16* hid_lo = (u16*)alloc(2048ull*2048*2);
  u16* wqa_hi = (u16*)alloc(1536ull*2048*2);
  u16* wqa_lo = (u16*)alloc(1536ull*2048*2);
  u16* wqb_b  = (u16*)alloc(3072ull*1536*2);
  u16* wkva_b = (u16*)alloc(576ull*2048*2);
  u16* wkvb_b = (u16*)alloc(4096ull*512*2);
  u16* wo_b   = (u16*)alloc(2048ull*2048*2);
  u16* iwqb_hi= (u16*)alloc(4096ull*1536*2);
  u16* iwqb_lo= (u16*)alloc(4096ull*1536*2);
  u16* kiwp_hi= (u16*)alloc(160ull*2048*2);
  u16* kiwp_lo= (u16*)alloc(160ull*2048*2);
  float* kiwp_C=(float*)alloc(2048ull*160*4);
  u16* qr_hi  = (u16*)alloc(2048ull*1536*2);
  u16* qr_lo  = (u16*)alloc(2048ull*1536*2);
  u16* kv_b   = (u16*)alloc(2048ull*512*2);
  float* kpe  = (float*)alloc(2048ull*64*4);
  u16* k_b    = (u16*)alloc(2048ull*16*192*2);
  u16* v_b    = (u16*)alloc(2048ull*16*128*2);
  u16* ki_hi  = (u16*)alloc(2048ull*128*2);
  u16* ki_lo  = (u16*)alloc(2048ull*128*2);
  u64* bits   = (u64*)alloc(2048ull*32*8);
  u16* attn_b = (u16*)alloc(2048ull*2048*2);
  float* reg1 = (float*)alloc(2048ull*4096*4); // sequential lifetimes
  if(ws_size < off) return; // loud failure if workspace too small

  // aliases (lifetime-checked)
  // q_b occupies wqa_hi AND wqa_lo (12.58MB = 2048x3072 bf16) -> wqa_lo is NOT free!
  u16* q_b      = wqa_hi;            // after wq_a last read (qr gemm); spans hi+lo
  u16* qi_hi    = hid_hi;            // after hidden last read (kiwp gemm); spans hid_hi+hid_lo
  u16* qi_lo    = iwqb_hi;           // after idx_wq_b last read (qi gemm); spans into iwqb_lo
  float* ml     = (float*)qr_lo;     // qr_lo dead after qi gemm; 1MB needed << 6.29MB  [R2 bug: was wqa_lo = q_b upper half]
  float* qr_pre = reg1;
  float* q_pre  = reg1;
  float* kva_part = reg1;            // 2 planes x 2048x576
  float* kvall  = reg1 + 4ull*1024*1024;
  float* kvp    = reg1;
  float* kiwp_part = reg1;           // 8 planes x 2048x160
  float* qi_pre = reg1;
  float* iscore = reg1;
  u16* Opart    = (u16*)reg1;        // after topk consumes iscore

  auto G1 = [&](const u16* A,int lda,const u16* B,int ldb,float* C,int ldc,int M,int N,int K,int z){
    dim3 g((unsigned)((N+127)/128), (unsigned)((M+127)/128), (unsigned)z);
    gemm_glds<0><<<g,256,0,stream>>>(A,nullptr,lda,B,nullptr,ldb,C,ldc,M,N,K);
  };
  auto G3 = [&](const u16* Ah,const u16* Al,int lda,const u16* Bh,const u16* Bl,int ldb,float* C,int ldc,int M,int N,int K,int z){
    dim3 g((unsigned)((N+127)/128), (unsigned)((M+127)/128), (unsigned)z);
    gemm_glds<1><<<g,256,0,stream>>>(Ah,Al,lda,Bh,Bl,ldb,C,ldc,M,N,K);
  };

  // converts
  cvt_split_v4<<<1024,256,0,stream>>>(hs, hid_hi, hid_lo, 2048*2048/4);
  cvt_split_v4<<<1024,256,0,stream>>>(wqa, wqa_hi, wqa_lo, 1536*2048/4);
  cvt_split_v4<<<1024,256,0,stream>>>(iwqb, iwqb_hi, iwqb_lo, 4096*1536/4);
  cvt_split_v4<<<256,256,0,stream>>>(iwk, kiwp_hi, kiwp_lo, 128*2048/4);
  cvt_split_v4<<<64,256,0,stream>>>(iwp, kiwp_hi+128*2048, kiwp_lo+128*2048, 32*2048/4);
  cvt_bf16_v4<<<1024,256,0,stream>>>(wqbw, wqb_b, 3072*1536/4);
  cvt_bf16_v4<<<512,256,0,stream>>>(wkva, wkva_b, 576*2048/4);
  cvt_bf16_v4<<<512,256,0,stream>>>(wkvb, wkvb_b, 4096*512/4);
  cvt_bf16_v4<<<1024,256,0,stream>>>(wow, wo_b, 2048*2048/4);

  // qr = rmsnorm(hidden @ wq_a^T)  [fused 3-pass split GEMM]
  G3(hid_hi,hid_lo,2048, wqa_hi,wqa_lo,2048, qr_pre,1536, 2048,1536,2048, 1);
  rmsnorm_qr_split<<<2048,256,0,stream>>>(qr_pre, qnw, qr_hi, qr_lo);

  // q path
  G1(qr_hi,1536, wqb_b,1536, q_pre,3072, 2048,3072,1536, 1);
  rope_q_cvt<<<2048,256,0,stream>>>(q_pre, fcos, fsin, q_b);

  // kv path (split-K z=2)
  G1(hid_hi,2048, wkva_b,2048, kva_part,576, 2048,576,2048, 2);
  ksum<<<1024,256,0,stream>>>(kva_part, kvall, 2048*576/4, 2, (size_t)2048*576/4);
  kv_norm_rope<<<2048,256,0,stream>>>(kvall, kvnw, fcos, fsin, kv_b, kpe);
  G1(kv_b,512, wkvb_b,512, kvp,4096, 2048,4096,512, 1);
  assemble_kv<<<2048,256,0,stream>>>(kvp, kpe, k_b, v_b);

  // indexer ki + wts packed (N=160, split-K z=8, fused 3-pass)
  G3(hid_hi,hid_lo,2048, kiwp_hi,kiwp_lo,2048, kiwp_part,160, 2048,160,2048, 8);
  ksum<<<1024,256,0,stream>>>(kiwp_part, kiwp_C, 2048*160/4, 8, (size_t)2048*160/4);
  ki_ln_rope_split<<<2048,128,0,stream>>>(kiwp_C, iknw, iknb, fcos, fsin, ki_hi, ki_lo);

  // indexer qi (fused 3-pass)
  G3(qr_hi,qr_lo,1536, iwqb_hi,iwqb_lo,1536, qi_pre,4096, 2048,4096,1536, 1);
  qi_rope_split<<<2048,256,0,stream>>>(qi_pre, fcos, fsin, qi_hi, qi_lo);

  // fused index scores (causal 64x64 tiles), exact top-512 mask
  idx_scores<<<528,256,0,stream>>>(qi_hi, qi_lo, ki_hi, ki_lo, kiwp_C, iscore);
  topk_mask<<<2048,256,0,stream>>>(iscore, bits);

  // attention (split-T) + combine + output projection
  flash_attn<<<dim3(40,16),256,0,stream>>>(q_b, k_b, v_b, bits, attn_b, Opart, ml);
  flash_combine<<<192,256,0,stream>>>(Opart, ml, attn_b);
  G1(attn_b,2048, wo_b,2048, outp,2048, 2048,2048,2048, 1);
}

// Round 4
// 670.501 us; speedup vs baseline: 1.7701x; 1.0833x over previous
//
#include <hip/hip_runtime.h>
#include <stdint.h>

typedef unsigned int uint;
typedef unsigned short u16;
typedef unsigned long long u64;

typedef float  f32x4 __attribute__((ext_vector_type(4)));
typedef uint   u32x4 __attribute__((ext_vector_type(4)));
typedef u16    u16x4 __attribute__((ext_vector_type(4)));
typedef u16    u16x8 __attribute__((ext_vector_type(8)));
typedef __bf16 bf16x8 __attribute__((ext_vector_type(8)));

#define DEV static __device__ __forceinline__
#define MFMA(a,b,c) __builtin_amdgcn_mfma_f32_16x16x32_bf16((a),(b),(c),0,0,0)
#define GLDS(src,dst) __builtin_amdgcn_global_load_lds((const __attribute__((address_space(1))) void*)(src),(__attribute__((address_space(3))) void*)(dst),16,0,0)

DEV u16 f2bf(float x){ union{float f;uint u;} v; v.f=x; return (u16)((v.u + 0x7fffu + ((v.u>>16)&1u))>>16); }
DEV float bf2f(u16 b){ union{uint u;float f;} v; v.u=((uint)b)<<16; return v.f; }
DEV int imin(int a,int b){ return a<b?a:b; }

// ---------------- converts ----------------
__global__ void cvt_bf16_v4(const float* __restrict__ in, u16* __restrict__ out, int n4){
  int i = blockIdx.x*blockDim.x + threadIdx.x;
  int st = gridDim.x*blockDim.x;
  for(; i<n4; i+=st){
    f32x4 x = reinterpret_cast<const f32x4*>(in)[i];
    u16x4 y;
    #pragma unroll
    for(int j=0;j<4;j++) y[j] = f2bf(x[j]);
    reinterpret_cast<u16x4*>(out)[i] = y;
  }
}

__global__ void cvt_split_v4(const float* __restrict__ in, u16* __restrict__ hi, u16* __restrict__ lo, int n4){
  int i = blockIdx.x*blockDim.x + threadIdx.x;
  int st = gridDim.x*blockDim.x;
  for(; i<n4; i+=st){
    f32x4 x = reinterpret_cast<const f32x4*>(in)[i];
    u16x4 h, l;
    #pragma unroll
    for(int j=0;j<4;j++){
      u16 hb = f2bf(x[j]); h[j]=hb;
      l[j] = f2bf(x[j] - bf2f(hb));
    }
    reinterpret_cast<u16x4*>(hi)[i] = h;
    reinterpret_cast<u16x4*>(lo)[i] = l;
  }
}

// ---------------- GEMM (global_load_lds staging, m97 structure) ----------------
DEV void stage128x32(const u16* __restrict__ gbase, int ld, int row0, int maxrow, int k0, u16* lds){
  int tid = threadIdx.x, w = tid>>6, l = tid&63;
  #pragma unroll
  for(int j=0;j<2;j++){
    int seg = w + j*4;
    int row = seg*16 + (l>>2);
    int gr = row0 + row; if(gr > maxrow) gr = maxrow;
    const u16* g = gbase + (size_t)gr*ld + k0 + (l&3)*8;
    GLDS(g, lds + seg*512);
  }
}

template<int SPLIT>
__global__ __launch_bounds__(256,2) void gemm_glds(
    const u16* __restrict__ Ah, const u16* __restrict__ Al, int lda,
    const u16* __restrict__ Bh, const u16* __restrict__ Bl, int ldb,
    float* __restrict__ C, int ldc, int M, int N, int K)
{
  __shared__ u16 sAh[128*32];
  __shared__ u16 sBh[128*32];
  __shared__ u16 sAl[SPLIT?128*32:8];
  __shared__ u16 sBl[SPLIT?128*32:8];
  const int tid = threadIdx.x;
  const int w = tid>>6, l = tid&63;
  const int wr = w>>1, wc = w&1;
  const int l15 = l&15, l16 = l>>4;

  int gx = gridDim.x;
  int nwg = gx*gridDim.y;
  int orig = blockIdx.x + gx*blockIdx.y;
  int qq = nwg>>3, rr = nwg&7, xc = orig&7, oo = orig>>3;
  int wg = (xc<rr ? xc*(qq+1) : rr*(qq+1)+(xc-rr)*qq) + oo;
  int m0 = (wg/gx)*128, n0 = (wg%gx)*128;

  int kz = K/(int)gridDim.z;
  int kbeg = blockIdx.z*kz;

  f32x4 acc[4][4];
  #pragma unroll
  for(int m=0;m<4;m++)
    #pragma unroll
    for(int n=0;n<4;n++) acc[m][n] = f32x4{0.f,0.f,0.f,0.f};

  for(int k0=kbeg; k0<kbeg+kz; k0+=32){
    __syncthreads();
    stage128x32(Ah, lda, m0, M-1, k0, sAh);
    stage128x32(Bh, ldb, n0, N-1, k0, sBh);
    if(SPLIT){
      stage128x32(Al, lda, m0, M-1, k0, sAl);
      stage128x32(Bl, ldb, n0, N-1, k0, sBl);
    }
    asm volatile("s_waitcnt vmcnt(0)" ::: "memory");
    __syncthreads();
    bf16x8 ah[4], bh[4];
    #pragma unroll
    for(int m=0;m<4;m++) ah[m] = *reinterpret_cast<const bf16x8*>(&sAh[(wr*64+m*16+l15)*32 + l16*8]);
    #pragma unroll
    for(int n=0;n<4;n++) bh[n] = *reinterpret_cast<const bf16x8*>(&sBh[(wc*64+n*16+l15)*32 + l16*8]);
    #pragma unroll
    for(int m=0;m<4;m++)
      #pragma unroll
      for(int n=0;n<4;n++) acc[m][n] = MFMA(ah[m], bh[n], acc[m][n]);
    if(SPLIT){
      bf16x8 t[4];
      #pragma unroll
      for(int n=0;n<4;n++) t[n] = *reinterpret_cast<const bf16x8*>(&sBl[(wc*64+n*16+l15)*32 + l16*8]);
      #pragma unroll
      for(int m=0;m<4;m++)
        #pragma unroll
        for(int n=0;n<4;n++) acc[m][n] = MFMA(ah[m], t[n], acc[m][n]);
      #pragma unroll
      for(int m=0;m<4;m++) t[m] = *reinterpret_cast<const bf16x8*>(&sAl[(wr*64+m*16+l15)*32 + l16*8]);
      #pragma unroll
      for(int m=0;m<4;m++)
        #pragma unroll
        for(int n=0;n<4;n++) acc[m][n] = MFMA(t[m], bh[n], acc[m][n]);
    }
  }
  float* Cp = C + (size_t)blockIdx.z*M*ldc;
  #pragma unroll
  for(int m=0;m<4;m++){
    int row = m0 + wr*64 + m*16 + l16*4;
    #pragma unroll
    for(int n=0;n<4;n++){
      int col = n0 + wc*64 + n*16 + l15;
      if(col < N){
        #pragma unroll
        for(int r=0;r<4;r++){
          int rrow = row + r;
          if(rrow < M) Cp[(size_t)rrow*ldc + col] = acc[m][n][r];
        }
      }
    }
  }
}

__global__ void ksum(const float* __restrict__ P, float* __restrict__ C, int n4, int z, size_t plane4){
  int i = blockIdx.x*blockDim.x + threadIdx.x;
  int st = gridDim.x*blockDim.x;
  for(; i<n4; i+=st){
    f32x4 s = reinterpret_cast<const f32x4*>(P)[i];
    for(int c=1;c<z;c++) s += reinterpret_cast<const f32x4*>(P)[(size_t)i + (size_t)c*plane4];
    reinterpret_cast<f32x4*>(C)[i] = s;
  }
}

// ---------------- norms / rope ----------------
__global__ __launch_bounds__(256) void rmsnorm_qr_split(
    const float* __restrict__ in, const float* __restrict__ w,
    u16* __restrict__ hi, u16* __restrict__ lo)
{
  int s = blockIdx.x, tid = threadIdx.x;
  __shared__ float red[4];
  const float* x = in + (size_t)s*1536;
  float xv[6]; float ss=0.f;
  #pragma unroll
  for(int i=0;i<6;i++){ xv[i] = x[tid + i*256]; ss += xv[i]*xv[i]; }
  #pragma unroll
  for(int o=32;o>0;o>>=1) ss += __shfl_down(ss,o,64);
  if((tid&63)==0) red[tid>>6]=ss;
  __syncthreads();
  float total = red[0]+red[1]+red[2]+red[3];
  float scale = rsqrtf(total*(1.0f/1536.0f) + 1e-6f);
  #pragma unroll
  for(int i=0;i<6;i++){
    int c = tid + i*256;
    float vv = xv[i]*scale*w[c];
    u16 hv = f2bf(vv);
    hi[(size_t)s*1536+c]=hv;
    lo[(size_t)s*1536+c]=f2bf(vv - bf2f(hv));
  }
}

__global__ __launch_bounds__(256) void kv_norm_rope(
    const float* __restrict__ kvall, const float* __restrict__ w,
    const float* __restrict__ fcos, const float* __restrict__ fsin,
    u16* __restrict__ kvb, float* __restrict__ kpe)
{
  int s = blockIdx.x, tid = threadIdx.x;
  __shared__ float red[4];
  const float* x = kvall + (size_t)s*576;
  float xv[2]; float ss=0.f;
  #pragma unroll
  for(int i=0;i<2;i++){ xv[i]=x[tid+i*256]; ss+=xv[i]*xv[i]; }
  #pragma unroll
  for(int o=32;o>0;o>>=1) ss += __shfl_down(ss,o,64);
  if((tid&63)==0) red[tid>>6]=ss;
  __syncthreads();
  float total = red[0]+red[1]+red[2]+red[3];
  float scale = rsqrtf(total*(1.0f/512.0f)+1e-6f);
  #pragma unroll
  for(int i=0;i<2;i++){ int c=tid+i*256; kvb[(size_t)s*512+c]=f2bf(xv[i]*scale*w[c]); }
  if(tid<32){
    float c0=fcos[(size_t)s*32+tid], s_=fsin[(size_t)s*32+tid];
    float x0=x[512+2*tid], x1=x[513+2*tid];
    kpe[(size_t)s*64+2*tid]   = x0*c0 - x1*s_;
    kpe[(size_t)s*64+2*tid+1] = x0*s_ + x1*c0;
  }
}

__global__ __launch_bounds__(256) void rope_q_cvt(const float* __restrict__ qpre,
    const float* __restrict__ fcos, const float* __restrict__ fsin, u16* __restrict__ qb)
{
  int s = blockIdx.x;
  const float* rowp = qpre + (size_t)s*3072;
  u16* op = qb + (size_t)s*3072;
  for(int idx=threadIdx.x; idx<3072; idx+=256){
    int hh = idx/192, d = idx - hh*192;
    float vv;
    if(d < 128) vv = rowp[hh*192 + d];
    else{
      int i2 = (d-128)>>1;
      float c0 = fcos[(size_t)s*32+i2], s_ = fsin[(size_t)s*32+i2];
      float x0 = rowp[hh*192 + 128 + 2*i2], x1 = rowp[hh*192 + 129 + 2*i2];
      vv = ((d&1)==0) ? (x0*c0 - x1*s_) : (x0*s_ + x1*c0);
    }
    op[idx] = f2bf(vv);
  }
}

__global__ __launch_bounds__(256) void qi_rope_split(const float* __restrict__ qpre,
    const float* __restrict__ fcos, const float* __restrict__ fsin,
    u16* __restrict__ hi, u16* __restrict__ lo)
{
  int s = blockIdx.x;
  const float* rowp = qpre + (size_t)s*4096;
  for(int idx=threadIdx.x; idx<4096; idx+=256){
    int hh = idx>>7, d = idx&127;
    const float* hb = rowp + (hh<<7);
    float vv;
    if(d<32){ float c0=fcos[(size_t)s*32+d], s_=fsin[(size_t)s*32+d]; vv = hb[d]*c0 - hb[d+32]*s_; }
    else if(d<64){ int i2=d-32; float c0=fcos[(size_t)s*32+i2], s_=fsin[(size_t)s*32+i2]; vv = hb[i2]*s_ + hb[d]*c0; }
    else vv = hb[d];
    u16 hv = f2bf(vv);
    hi[(size_t)s*4096+idx]=hv;
    lo[(size_t)s*4096+idx]=f2bf(vv - bf2f(hv));
  }
}

__global__ __launch_bounds__(128) void ki_ln_rope_split(
    const float* __restrict__ kpre, const float* __restrict__ w, const float* __restrict__ bb,
    const float* __restrict__ fcos, const float* __restrict__ fsin,
    u16* __restrict__ hi, u16* __restrict__ lo)
{
  int s = blockIdx.x, tid = threadIdx.x;
  __shared__ float red[2];
  __shared__ float ybuf[128];
  float x = kpre[(size_t)s*160 + tid];
  float v = x;
  #pragma unroll
  for(int o=32;o>0;o>>=1) v += __shfl_down(v,o,64);
  if((tid&63)==0) red[tid>>6]=v;
  __syncthreads();
  float mean = (red[0]+red[1])*(1.f/128.f);
  __syncthreads();
  float dx = x - mean;
  v = dx*dx;
  #pragma unroll
  for(int o=32;o>0;o>>=1) v += __shfl_down(v,o,64);
  if((tid&63)==0) red[tid>>6]=v;
  __syncthreads();
  float var = (red[0]+red[1])*(1.f/128.f);
  float y = dx*rsqrtf(var+1e-5f)*w[tid] + bb[tid];
  ybuf[tid]=y;
  __syncthreads();
  float r;
  if(tid<32){ float c0=fcos[(size_t)s*32+tid], s_=fsin[(size_t)s*32+tid]; r = ybuf[tid]*c0 - ybuf[tid+32]*s_; }
  else if(tid<64){ int i2=tid-32; float c0=fcos[(size_t)s*32+i2], s_=fsin[(size_t)s*32+i2]; r = ybuf[i2]*s_ + ybuf[tid]*c0; }
  else r = y;
  u16 hv=f2bf(r);
  hi[(size_t)s*128+tid]=hv;
  lo[(size_t)s*128+tid]=f2bf(r-bf2f(hv));
}

__global__ void assemble_k(const float* __restrict__ kvp, const float* __restrict__ kpe,
                           u16* __restrict__ kb){
  int i0 = blockIdx.x*blockDim.x + threadIdx.x;
  int st = gridDim.x*blockDim.x;
  for(int idx=i0; idx<2048*16*192; idx+=st){
    int s = idx/3072; int rrem = idx - s*3072; int hh = rrem/192; int d = rrem - hh*192;
    float val = (d<128) ? kvp[(size_t)s*4096 + hh*256 + d] : kpe[(size_t)s*64 + (d-128)];
    kb[idx] = f2bf(val);
  }
}

// transpose V: kvp[s][h*256+128+d] -> v_t[h][d][s]  (LDS-tiled, bf16 out)
__global__ __launch_bounds__(256) void transpose_v(const float* __restrict__ kvp, u16* __restrict__ vt){
  __shared__ u16 T[64*136];
  int s0 = blockIdx.x*64, h = blockIdx.y;
  int tid = threadIdx.x;
  #pragma unroll
  for(int i=0;i<8;i++){
    int ch = i*256 + tid;          // 2048 chunks of 4 floats
    int r = ch>>5, cc = ch&31;
    f32x4 x = *reinterpret_cast<const f32x4*>(&kvp[(size_t)(s0+r)*4096 + h*256 + 128 + cc*4]);
    u16x4 y;
    #pragma unroll
    for(int j=0;j<4;j++) y[j] = f2bf(x[j]);
    *reinterpret_cast<u16x4*>(&T[r*136 + cc*4]) = y;
  }
  __syncthreads();
  #pragma unroll
  for(int i=0;i<4;i++){
    int ch = i*256 + tid;          // 1024 chunks of 8 u16
    int d = ch>>3, sc = ch&7;
    u16x8 y;
    #pragma unroll
    for(int j=0;j<8;j++) y[j] = T[(sc*8+j)*136 + d];
    *reinterpret_cast<u16x8*>(&vt[((size_t)h*128 + d)*2048 + s0 + sc*8]) = y;
  }
}

// ---------------- fused indexer scores v2 (128x128 tile, K-resident, Q dbuf) ----------------
DEV void isc_pass128(const u16* __restrict__ Q, const u16* __restrict__ Kb,
                     f32x4 (&sc)[4][2], int wm, int wn, int l15, int l16){
  #pragma unroll
  for(int ks=0;ks<4;ks++){
    bf16x8 a[4], b[2];
    #pragma unroll
    for(int m=0;m<4;m++){
      int row = wm*64 + m*16 + l15;
      a[m] = *reinterpret_cast<const bf16x8*>(&Q[row*128 + ((((ks<<2)+l16) ^ (row&7))<<3)]);
    }
    #pragma unroll
    for(int n=0;n<2;n++){
      int row = wn*32 + n*16 + l15;
      b[n] = *reinterpret_cast<const bf16x8*>(&Kb[row*128 + ((((ks<<2)+l16) ^ (row&7))<<3)]);
    }
    #pragma unroll
    for(int m=0;m<4;m++)
      #pragma unroll
      for(int n=0;n<2;n++) sc[m][n] = MFMA(a[m], b[n], sc[m][n]);
  }
}

__global__ __launch_bounds__(512,2) void idx_scores2(
    const u16* __restrict__ qih, const u16* __restrict__ qil,
    const u16* __restrict__ kih, const u16* __restrict__ kil,
    const float* __restrict__ wts, float* __restrict__ outp)
{
  __shared__ u16 Kh[128*128];
  __shared__ u16 Kl[128*128];
  __shared__ u16 Qb[2][128*128];
  int bid = blockIdx.x;
  int si=0, t=bid;
  while(t >= si+1){ t -= si+1; si++; }
  int s0 = si*128, t0 = t*128;
  int tid=threadIdx.x, w=tid>>6, l=tid&63;
  int wm=w>>2, wn=w&3, l15=l&15, l16=l>>4;
  // stage K (hi+lo) once: 4 rounds each of 8KB
  #pragma unroll
  for(int rnd=0;rnd<4;rnd++){
    int cid = rnd*512 + w*64 + l;
    int row = cid>>4, cc = cid&15;
    int scc = cc ^ (row&7);
    GLDS(kih + (size_t)(t0+row)*128 + scc*8, Kh + rnd*4096 + w*512);
    GLDS(kil + (size_t)(t0+row)*128 + scc*8, Kl + rnd*4096 + w*512);
  }
  // prefetch Q stage 0 (h=0, hi)
  #pragma unroll
  for(int rnd=0;rnd<4;rnd++){
    int cid = rnd*512 + w*64 + l;
    int row = cid>>4, cc = cid&15;
    int scc = cc ^ (row&7);
    GLDS(qih + (size_t)(s0+row)*4096 + 0*128 + scc*8, Qb[0] + rnd*4096 + w*512);
  }
  asm volatile("s_waitcnt vmcnt(0)" ::: "memory");
  __syncthreads();
  f32x4 accI[4][2], sc[4][2];
  #pragma unroll
  for(int m=0;m<4;m++) for(int n=0;n<2;n++) accI[m][n] = f32x4{0.f,0.f,0.f,0.f};
  const float cscale = 0.015625f; // HI^-0.5 * DI^-0.5
  for(int s=0;s<64;s++){
    int nxt = s+1;
    if(nxt < 64){
      const u16* src = (nxt&1) ? qil : qih;
      int hh = nxt>>1;
      u16* dst = Qb[nxt&1];
      #pragma unroll
      for(int rnd=0;rnd<4;rnd++){
        int cid = rnd*512 + w*64 + l;
        int row = cid>>4, cc = cid&15;
        int scc = cc ^ (row&7);
        GLDS(src + (size_t)(s0+row)*4096 + hh*128 + scc*8, dst + rnd*4096 + w*512);
      }
    }
    const u16* Q = Qb[s&1];
    if((s&1)==0){
      #pragma unroll
      for(int m=0;m<4;m++) for(int n=0;n<2;n++) sc[m][n] = f32x4{0.f,0.f,0.f,0.f};
      isc_pass128(Q, Kh, sc, wm, wn, l15, l16);
      isc_pass128(Q, Kl, sc, wm, wn, l15, l16);
    } else {
      isc_pass128(Q, Kh, sc, wm, wn, l15, l16);
      int hh = s>>1;
      #pragma unroll
      for(int m=0;m<4;m++)
        #pragma unroll
        for(int r=0;r<4;r++){
          float wv = wts[(size_t)(s0+wm*64+m*16+l16*4+r)*160 + 128 + hh]*cscale;
          #pragma unroll
          for(int n=0;n<2;n++) accI[m][n][r] += fmaxf(sc[m][n][r],0.f)*wv;
        }
    }
    asm volatile("s_waitcnt vmcnt(0)" ::: "memory");
    __syncthreads();
  }
  #pragma unroll
  for(int m=0;m<4;m++)
    #pragma unroll
    for(int n=0;n<2;n++)
      #pragma unroll
      for(int r=0;r<4;r++)
        outp[(size_t)(s0+wm*64+m*16+l16*4+r)*2048 + t0 + wn*32 + n*16 + l15] = accI[m][n][r];
}

// ---------------- exact top-512 per row -> bitmask ----------------
DEV uint fkey(float f){ union{float f;uint u;} v; v.f=f; return (v.u & 0x80000000u) ? ~v.u : (v.u | 0x80000000u); }

__global__ __launch_bounds__(256) void topk_mask(const float* __restrict__ scores, u64* __restrict__ bits){
  int s = blockIdx.x;
  int n = s+1;
  int tid = threadIdx.x;
  const float* row = scores + (size_t)s*2048;
  if(n <= 512){
    for(int wI=tid; wI<32; wI+=256){
      u64 m=0; int base=wI*64;
      if(base < n){ int cnt=n-base; m = (cnt>=64)? ~0ull : ((1ull<<cnt)-1ull); }
      bits[(size_t)s*32+wI]=m;
    }
    return;
  }
  __shared__ uint hist[256];
  __shared__ uint sh_B, sh_k;
  __shared__ uint wcnt[32];
  uint prefix=0, k=512;
  for(int shift=24; shift>=0; shift-=8){
    hist[tid]=0;
    __syncthreads();
    for(int t2=tid;t2<n;t2+=256){
      uint u = fkey(row[t2]);
      bool ok = (shift==24) || ((u>>(shift+8)) == (prefix>>(shift+8)));
      if(ok) atomicAdd(&hist[(u>>shift)&255u],1u);
    }
    __syncthreads();
    if(tid==0){
      uint c=0;
      for(int b2=255;b2>=0;b2--){
        c += hist[b2];
        if(c>=k){ sh_B=(uint)b2; sh_k = k-(c-hist[b2]); break; }
      }
    }
    __syncthreads();
    prefix |= sh_B<<shift;
    k = sh_k;
    __syncthreads();
  }
  uint thr = prefix;
  if(tid<32) wcnt[tid]=0;
  __syncthreads();
  int nw = (n+63)>>6;
  if(tid < nw){
    int base=tid*64, end = base+64; if(end>n) end=n;
    uint c=0;
    for(int t2=base;t2<end;t2++) if(fkey(row[t2])==thr) c++;
    wcnt[tid]=c;
  }
  __syncthreads();
  if(tid==0){
    uint runv=0;
    for(int i=0;i<32;i++){ uint c=wcnt[i]; wcnt[i]=runv; runv+=c; }
  }
  __syncthreads();
  if(tid<32){
    u64 m=0; int base=tid*64;
    if(base<n){
      uint rank = wcnt[tid];
      int end = base+64; if(end>n) end=n;
      for(int t2=base;t2<end;t2++){
        uint u = fkey(row[t2]);
        if(u>thr) m |= (1ull<<(t2-base));
        else if(u==thr){ if(rank<k) m |= (1ull<<(t2-base)); rank++; }
      }
    }
    bits[(size_t)s*32+tid]=m;
  }
}

// ---------------- flash attention v2: 64-row blocks, glds staging, V^T global ----------------
__global__ __launch_bounds__(256,3) void flash_attn(
    const u16* __restrict__ q, const u16* __restrict__ k, const u16* __restrict__ vt,
    const u64* __restrict__ bits, u16* __restrict__ o,
    u16* __restrict__ Opart, float* __restrict__ ml)
{
  __shared__ u16 Ks[64*192];   // linear rows of 384B, XOR-swz source
  __shared__ u16 Vt[128*64];   // d-major rows of 128B, XOR-swz source
  __shared__ u16 Pl[64*72];
  int h = blockIdx.y;
  int pp = blockIdx.x;  // 0..79, heavy first
  int sblk=0, chunk=0;
  for(int i=0;i<32;i++){
    int sb = 31-i; int ncc = (sb>>3)+1;
    if(pp < ncc){ sblk=sb; chunk=pp; break; }
    pp -= ncc;
  }
  int nc = (sblk>>3)+1, ntiles = sblk+1, s0 = sblk*64;
  int tid=threadIdx.x, w=tid>>6, l=tid&63;
  int l15=l&15, l16=l>>4;
  const float sscale = 0.07216878364870323f; // 1/sqrt(192)
  bf16x8 qf[6];
  #pragma unroll
  for(int ks=0;ks<6;ks++)
    qf[ks] = *reinterpret_cast<const bf16x8*>(&q[((size_t)(s0+w*16+l15)*16 + h)*192 + ks*32 + l16*8]);
  f32x4 Oa[8];
  #pragma unroll
  for(int n=0;n<8;n++) Oa[n] = f32x4{0.f,0.f,0.f,0.f};
  float mrun[4], lrun[4];
  #pragma unroll
  for(int r=0;r<4;r++){ mrun[r]=-__builtin_inff(); lrun[r]=0.f; }
  int tt0 = chunk*8, tt1 = imin(tt0+8, ntiles);
  for(int tt=tt0; tt<tt1; tt++){
    int t0 = tt*64;
    __syncthreads();
    // stage K: 6 rounds of 4KB
    #pragma unroll
    for(int rnd=0;rnd<6;rnd++){
      int cid = rnd*256 + w*64 + l;
      int row = cid/24, cc = cid - row*24;
      int scc = cc ^ (row&7);
      GLDS(k + ((size_t)(t0+row)*16 + h)*192 + scc*8, Ks + rnd*2048 + w*512);
    }
    // stage V^T: 4 rounds
    #pragma unroll
    for(int rnd=0;rnd<4;rnd++){
      int cid = rnd*256 + w*64 + l;
      int row = cid>>3, cc = cid&7;
      int scc = cc ^ (row&7);
      GLDS(vt + ((size_t)h*128 + row)*2048 + t0 + scc*8, Vt + rnd*2048 + w*512);
    }
    asm volatile("s_waitcnt vmcnt(0)" ::: "memory");
    __syncthreads();
    f32x4 S[4];
    #pragma unroll
    for(int n=0;n<4;n++) S[n] = f32x4{0.f,0.f,0.f,0.f};
    #pragma unroll
    for(int ks=0;ks<6;ks++){
      bf16x8 b[4];
      #pragma unroll
      for(int n=0;n<4;n++){
        int row = n*16+l15;
        b[n] = *reinterpret_cast<const bf16x8*>(&Ks[row*192 + ((((ks<<2)+l16) ^ (row&7))<<3)]);
      }
      #pragma unroll
      for(int n=0;n<4;n++) S[n] = MFMA(qf[ks], b[n], S[n]);
    }
    #pragma unroll
    for(int r=0;r<4;r++){
      int srow = s0 + w*16 + l16*4 + r;
      u64 wrd = bits[(size_t)srow*32 + (t0>>6)];
      float mx = -__builtin_inff();
      #pragma unroll
      for(int n=0;n<4;n++){
        int bitp = n*16 + l15;
        int tcol = t0 + bitp;
        bool ok = (tcol <= srow) && ((wrd>>bitp)&1ull);
        float val = ok ? S[n][r]*sscale : -__builtin_inff();
        S[n][r] = val;
        mx = fmaxf(mx, val);
      }
      #pragma unroll
      for(int off=1;off<16;off<<=1) mx = fmaxf(mx, __shfl_xor(mx, off, 64));
      float mold = mrun[r];
      float mnew = fmaxf(mold, mx);
      bool inf0 = (mnew == -__builtin_inff());
      float alpha = inf0 ? 1.f : __expf(mold - mnew);
      float rs = 0.f;
      #pragma unroll
      for(int n=0;n<4;n++){
        float p = inf0 ? 0.f : __expf(S[n][r] - mnew);
        S[n][r] = p;
        rs += p;
      }
      #pragma unroll
      for(int off=1;off<16;off<<=1) rs += __shfl_xor(rs, off, 64);
      mrun[r]=mnew;
      lrun[r] = lrun[r]*alpha + rs;
      #pragma unroll
      for(int n=0;n<8;n++) Oa[n][r] *= alpha;
    }
    // P -> LDS (wave-private 16-row band)
    #pragma unroll
    for(int n=0;n<4;n++)
      #pragma unroll
      for(int r=0;r<4;r++)
        Pl[(w*16+l16*4+r)*72 + n*16+l15] = f2bf(S[n][r]);
    #pragma unroll
    for(int ks=0;ks<2;ks++){
      bf16x8 a = *reinterpret_cast<const bf16x8*>(&Pl[(w*16+l15)*72 + ks*32 + l16*8]);
      bf16x8 bb[8];
      #pragma unroll
      for(int n=0;n<8;n++){
        int d = n*16+l15;
        bb[n] = *reinterpret_cast<const bf16x8*>(&Vt[d*64 + ((((ks<<2)+l16) ^ (d&7))<<3)]);
      }
      #pragma unroll
      for(int n=0;n<8;n++) Oa[n] = MFMA(a, bb[n], Oa[n]);
    }
  }
  if(nc == 1){
    #pragma unroll
    for(int r=0;r<4;r++){
      int srow = s0 + w*16 + l16*4 + r;
      float inv = 1.f/lrun[r];
      #pragma unroll
      for(int n=0;n<8;n++)
        o[(size_t)srow*2048 + h*128 + n*16 + l15] = f2bf(Oa[n][r]*inv);
    }
  } else {
    int part = ((h*32 + sblk)<<2) + chunk;
    u16* Op = Opart + (size_t)part*8192;
    #pragma unroll
    for(int r=0;r<4;r++){
      int rit = w*16 + l16*4 + r;
      #pragma unroll
      for(int n=0;n<8;n++)
        Op[rit*128 + n*16 + l15] = f2bf(Oa[n][r]);
      if(l15==0){
        ml[(size_t)part*128 + rit*2]   = mrun[r];
        ml[(size_t)part*128 + rit*2+1] = lrun[r];
      }
    }
  }
}

__global__ __launch_bounds__(256) void flash_combine(
    const u16* __restrict__ Opart, const float* __restrict__ ml, u16* __restrict__ o)
{
  int b = blockIdx.x;            // h*24 + (sblk-8)
  int h = b/24, sblk = 8 + (b%24);
  int nc = (sblk>>3)+1;          // 2..4
  int tid = threadIdx.x;
  int r = tid>>2, dq = (tid&3)*32;
  int s0 = sblk*64;
  int pbase = (h*32+sblk)<<2;
  float m[4], lv[4], wgt[4];
  float M = -__builtin_inff();
  for(int c=0;c<nc;c++){
    m[c]  = ml[(size_t)(pbase+c)*128 + r*2];
    lv[c] = ml[(size_t)(pbase+c)*128 + r*2 + 1];
    if(lv[c] > 0.f) M = fmaxf(M, m[c]);
  }
  float L = 0.f;
  for(int c=0;c<nc;c++){
    wgt[c] = (lv[c] > 0.f) ? __expf(m[c]-M) : 0.f;
    L += lv[c]*wgt[c];
  }
  float inv = 1.f/L;
  for(int dd=0; dd<32; dd+=8){
    float accv[8];
    #pragma unroll
    for(int j=0;j<8;j++) accv[j]=0.f;
    for(int c=0;c<nc;c++){
      u16x8 pv = *reinterpret_cast<const u16x8*>(&Opart[(size_t)(pbase+c)*8192 + r*128 + dq + dd]);
      #pragma unroll
      for(int j=0;j<8;j++) accv[j] += wgt[c]*bf2f(pv[j]);
    }
    u16x8 ov;
    #pragma unroll
    for(int j=0;j<8;j++) ov[j] = f2bf(accv[j]*inv);
    *reinterpret_cast<u16x8*>(&o[(size_t)(s0+r)*2048 + h*128 + dq + dd]) = ov;
  }
}

// ---------------- host ----------------
extern "C" void kernel_launch(void* const* d_in, const int* in_sizes, int n_in,
                              void* d_out, int out_size, void* d_ws, size_t ws_size,
                              hipStream_t stream)
{
  (void)in_sizes; (void)n_in; (void)out_size;
  const float* hs   = (const float*)d_in[0];
  const float* wqa  = (const float*)d_in[1];
  const float* qnw  = (const float*)d_in[2];
  const float* wqbw = (const float*)d_in[3];
  const float* wkva = (const float*)d_in[4];
  const float* kvnw = (const float*)d_in[5];
  const float* wkvb = (const float*)d_in[6];
  const float* wow  = (const float*)d_in[7];
  const float* iwqb = (const float*)d_in[8];
  const float* iwk  = (const float*)d_in[9];
  const float* iknw = (const float*)d_in[10];
  const float* iknb = (const float*)d_in[11];
  const float* iwp  = (const float*)d_in[12];
  const float* fcos = (const float*)d_in[13];
  const float* fsin = (const float*)d_in[14];
  float* outp = (float*)d_out;

  char* base = (char*)d_ws;
  size_t off = 0;
  auto alloc = [&](size_t bytes)->char*{ char* p = base+off; off += (bytes+255)&~(size_t)255; return p; };
  u16* hid_hi = (u16*)alloc(2048ull*2048*2);
  u16* hid_lo = (u16*)alloc(2048ull*2048*2);
  u16* wqa_hi = (u16*)alloc(1536ull*2048*2);
  u16* wqa_lo = (u16*)alloc(1536ull*2048*2);
  u16* wqb_b  = (u16*)alloc(3072ull*1536*2);
  u16* wkva_b = (u16*)alloc(576ull*2048*2);
  u16* wkvb_b = (u16*)alloc(4096ull*512*2);
  u16* wo_b   = (u16*)alloc(2048ull*2048*2);
  u16* iwqb_hi= (u16*)alloc(4096ull*1536*2);
  u16* iwqb_lo= (u16*)alloc(4096ull*1536*2);
  u16* kiwp_hi= (u16*)alloc(160ull*2048*2);
  u16* kiwp_lo= (u16*)alloc(160ull*2048*2);
  float* kiwp_C=(float*)alloc(2048ull*160*4);
  u16* qr_hi  = (u16*)alloc(2048ull*1536*2);
  u16* qr_lo  = (u16*)alloc(2048ull*1536*2);
  u16* kv_b   = (u16*)alloc(2048ull*512*2);
  float* kpe  = (float*)alloc(2048ull*64*4);
  u16* k_b    = (u16*)alloc(2048ull*16*192*2);
  u16* v_t    = (u16*)alloc(16ull*128*2048*2);   // [h][d][s]
  u16* ki_hi  = (u16*)alloc(2048ull*128*2);
  u16* ki_lo  = (u16*)alloc(2048ull*128*2);
  u64* bits   = (u64*)alloc(2048ull*32*8);
  u16* attn_b = (u16*)alloc(2048ull*2048*2);
  float* reg1 = (float*)alloc(2048ull*4096*4); // sequential lifetimes
  if(ws_size < off) return;

  // aliases (lifetime-checked)
  u16* q_b      = wqa_hi;            // spans wqa_hi+wqa_lo (12.58MB); wq_a dead after qr gemm
  u16* qi_hi    = hid_hi;            // spans hid_hi+hid_lo; hidden dead after kiwp gemm
  u16* qi_lo    = iwqb_hi;           // spans into iwqb_lo; idx_wq_b dead after qi gemm
  float* ml     = (float*)qr_lo;     // qr dead after qi gemm; 1MB << 6.29MB
  float* qr_pre = reg1;
  float* q_pre  = reg1;
  float* kva_part = reg1;
  float* kvall  = reg1 + 4ull*1024*1024;
  float* kvp    = reg1;
  float* kiwp_part = reg1;
  float* qi_pre = reg1;
  float* iscore = reg1;
  u16* Opart    = (u16*)reg1;        // 2048 parts x 16KB = 32MB <= 33.5MB; after topk consumes iscore

  auto G1 = [&](const u16* A,int lda,const u16* B,int ldb,float* C,int ldc,int M,int N,int K,int z){
    dim3 g((unsigned)((N+127)/128), (unsigned)((M+127)/128), (unsigned)z);
    gemm_glds<0><<<g,256,0,stream>>>(A,nullptr,lda,B,nullptr,ldb,C,ldc,M,N,K);
  };
  auto G3 = [&](const u16* Ah,const u16* Al,int lda,const u16* Bh,const u16* Bl,int ldb,float* C,int ldc,int M,int N,int K,int z){
    dim3 g((unsigned)((N+127)/128), (unsigned)((M+127)/128), (unsigned)z);
    gemm_glds<1><<<g,256,0,stream>>>(Ah,Al,lda,Bh,Bl,ldb,C,ldc,M,N,K);
  };

  // converts
  cvt_split_v4<<<1024,256,0,stream>>>(hs, hid_hi, hid_lo, 2048*2048/4);
  cvt_split_v4<<<1024,256,0,stream>>>(wqa, wqa_hi, wqa_lo, 1536*2048/4);
  cvt_split_v4<<<1024,256,0,stream>>>(iwqb, iwqb_hi, iwqb_lo, 4096*1536/4);
  cvt_split_v4<<<256,256,0,stream>>>(iwk, kiwp_hi, kiwp_lo, 128*2048/4);
  cvt_split_v4<<<64,256,0,stream>>>(iwp, kiwp_hi+128*2048, kiwp_lo+128*2048, 32*2048/4);
  cvt_bf16_v4<<<1024,256,0,stream>>>(wqbw, wqb_b, 3072*1536/4);
  cvt_bf16_v4<<<512,256,0,stream>>>(wkva, wkva_b, 576*2048/4);
  cvt_bf16_v4<<<512,256,0,stream>>>(wkvb, wkvb_b, 4096*512/4);
  cvt_bf16_v4<<<1024,256,0,stream>>>(wow, wo_b, 2048*2048/4);

  // qr = rmsnorm(hidden @ wq_a^T)
  G3(hid_hi,hid_lo,2048, wqa_hi,wqa_lo,2048, qr_pre,1536, 2048,1536,2048, 1);
  rmsnorm_qr_split<<<2048,256,0,stream>>>(qr_pre, qnw, qr_hi, qr_lo);

  // q path
  G1(qr_hi,1536, wqb_b,1536, q_pre,3072, 2048,3072,1536, 1);
  rope_q_cvt<<<2048,256,0,stream>>>(q_pre, fcos, fsin, q_b);

  // kv path
  G1(hid_hi,2048, wkva_b,2048, kva_part,576, 2048,576,2048, 2);
  ksum<<<1024,256,0,stream>>>(kva_part, kvall, 2048*576/4, 2, (size_t)2048*576/4);
  kv_norm_rope<<<2048,256,0,stream>>>(kvall, kvnw, fcos, fsin, kv_b, kpe);
  G1(kv_b,512, wkvb_b,512, kvp,4096, 2048,4096,512, 1);
  assemble_k<<<1024,256,0,stream>>>(kvp, kpe, k_b);
  transpose_v<<<dim3(32,16),256,0,stream>>>(kvp, v_t);

  // indexer ki + wts packed (N=160, split-K z=8)
  G3(hid_hi,hid_lo,2048, kiwp_hi,kiwp_lo,2048, kiwp_part,160, 2048,160,2048, 8);
  ksum<<<1024,256,0,stream>>>(kiwp_part, kiwp_C, 2048*160/4, 8, (size_t)2048*160/4);
  ki_ln_rope_split<<<2048,128,0,stream>>>(kiwp_C, iknw, iknb, fcos, fsin, ki_hi, ki_lo);

  // indexer qi
  G3(qr_hi,qr_lo,1536, iwqb_hi,iwqb_lo,1536, qi_pre,4096, 2048,4096,1536, 1);
  qi_rope_split<<<2048,256,0,stream>>>(qi_pre, fcos, fsin, qi_hi, qi_lo);

  // fused index scores (128x128 tiles, K-resident, Q dbuf) + exact top-512 mask
  idx_scores2<<<136,512,0,stream>>>(qi_hi, qi_lo, ki_hi, ki_lo, kiwp_C, iscore);
  topk_mask<<<2048,256,0,stream>>>(iscore, bits);

  // attention (64-row split-T) + combine + output projection
  flash_attn<<<dim3(80,16),256,0,stream>>>(q_b, k_b, v_t, bits, attn_b, Opart, ml);
  flash_combine<<<384,256,0,stream>>>(Opart, ml, attn_b);
  G1(attn_b,2048, wo_b,2048, outp,2048, 2048,2048,2048, 1);
}

// Round 5
// 645.315 us; speedup vs baseline: 1.8391x; 1.0390x over previous
//
#include <hip/hip_runtime.h>
#include <stdint.h>

typedef unsigned int uint;
typedef unsigned short u16;
typedef unsigned long long u64;

typedef float  f32x4 __attribute__((ext_vector_type(4)));
typedef uint   u32x4 __attribute__((ext_vector_type(4)));
typedef u16    u16x4 __attribute__((ext_vector_type(4)));
typedef u16    u16x8 __attribute__((ext_vector_type(8)));
typedef __bf16 bf16x8 __attribute__((ext_vector_type(8)));

#define DEV static __device__ __forceinline__
#define MFMA(a,b,c) __builtin_amdgcn_mfma_f32_16x16x32_bf16((a),(b),(c),0,0,0)
#define GLDS(src,dst) __builtin_amdgcn_global_load_lds((const __attribute__((address_space(1))) void*)(src),(__attribute__((address_space(3))) void*)(dst),16,0,0)

DEV u16 f2bf(float x){ union{float f;uint u;} v; v.f=x; return (u16)((v.u + 0x7fffu + ((v.u>>16)&1u))>>16); }
DEV float bf2f(u16 b){ union{uint u;float f;} v; v.u=((uint)b)<<16; return v.f; }
DEV int imin(int a,int b){ return a<b?a:b; }

// ---------------- converts ----------------
__global__ void cvt_bf16_v4(const float* __restrict__ in, u16* __restrict__ out, int n4){
  int i = blockIdx.x*blockDim.x + threadIdx.x;
  int st = gridDim.x*blockDim.x;
  for(; i<n4; i+=st){
    f32x4 x = reinterpret_cast<const f32x4*>(in)[i];
    u16x4 y;
    #pragma unroll
    for(int j=0;j<4;j++) y[j] = f2bf(x[j]);
    reinterpret_cast<u16x4*>(out)[i] = y;
  }
}

__global__ void cvt_split_v4(const float* __restrict__ in, u16* __restrict__ hi, u16* __restrict__ lo, int n4){
  int i = blockIdx.x*blockDim.x + threadIdx.x;
  int st = gridDim.x*blockDim.x;
  for(; i<n4; i+=st){
    f32x4 x = reinterpret_cast<const f32x4*>(in)[i];
    u16x4 h, l;
    #pragma unroll
    for(int j=0;j<4;j++){
      u16 hb = f2bf(x[j]); h[j]=hb;
      l[j] = f2bf(x[j] - bf2f(hb));
    }
    reinterpret_cast<u16x4*>(hi)[i] = h;
    reinterpret_cast<u16x4*>(lo)[i] = l;
  }
}

// ---------------- GEMM (global_load_lds staging, m97 structure) ----------------
DEV void stage128x32(const u16* __restrict__ gbase, int ld, int row0, int maxrow, int k0, u16* lds){
  int tid = threadIdx.x, w = tid>>6, l = tid&63;
  #pragma unroll
  for(int j=0;j<2;j++){
    int seg = w + j*4;
    int row = seg*16 + (l>>2);
    int gr = row0 + row; if(gr > maxrow) gr = maxrow;
    const u16* g = gbase + (size_t)gr*ld + k0 + (l&3)*8;
    GLDS(g, lds + seg*512);
  }
}

template<int SPLIT>
__global__ __launch_bounds__(256,2) void gemm_glds(
    const u16* __restrict__ Ah, const u16* __restrict__ Al, int lda,
    const u16* __restrict__ Bh, const u16* __restrict__ Bl, int ldb,
    float* __restrict__ C, int ldc, int M, int N, int K)
{
  __shared__ u16 sAh[128*32];
  __shared__ u16 sBh[128*32];
  __shared__ u16 sAl[SPLIT?128*32:8];
  __shared__ u16 sBl[SPLIT?128*32:8];
  const int tid = threadIdx.x;
  const int w = tid>>6, l = tid&63;
  const int wr = w>>1, wc = w&1;
  const int l15 = l&15, l16 = l>>4;

  int gx = gridDim.x;
  int nwg = gx*gridDim.y;
  int orig = blockIdx.x + gx*blockIdx.y;
  int qq = nwg>>3, rr = nwg&7, xc = orig&7, oo = orig>>3;
  int wg = (xc<rr ? xc*(qq+1) : rr*(qq+1)+(xc-rr)*qq) + oo;
  int m0 = (wg/gx)*128, n0 = (wg%gx)*128;

  int kz = K/(int)gridDim.z;
  int kbeg = blockIdx.z*kz;

  f32x4 acc[4][4];
  #pragma unroll
  for(int m=0;m<4;m++)
    #pragma unroll
    for(int n=0;n<4;n++) acc[m][n] = f32x4{0.f,0.f,0.f,0.f};

  for(int k0=kbeg; k0<kbeg+kz; k0+=32){
    __syncthreads();
    stage128x32(Ah, lda, m0, M-1, k0, sAh);
    stage128x32(Bh, ldb, n0, N-1, k0, sBh);
    if(SPLIT){
      stage128x32(Al, lda, m0, M-1, k0, sAl);
      stage128x32(Bl, ldb, n0, N-1, k0, sBl);
    }
    asm volatile("s_waitcnt vmcnt(0)" ::: "memory");
    __syncthreads();
    bf16x8 ah[4], bh[4];
    #pragma unroll
    for(int m=0;m<4;m++) ah[m] = *reinterpret_cast<const bf16x8*>(&sAh[(wr*64+m*16+l15)*32 + l16*8]);
    #pragma unroll
    for(int n=0;n<4;n++) bh[n] = *reinterpret_cast<const bf16x8*>(&sBh[(wc*64+n*16+l15)*32 + l16*8]);
    #pragma unroll
    for(int m=0;m<4;m++)
      #pragma unroll
      for(int n=0;n<4;n++) acc[m][n] = MFMA(ah[m], bh[n], acc[m][n]);
    if(SPLIT){
      bf16x8 t[4];
      #pragma unroll
      for(int n=0;n<4;n++) t[n] = *reinterpret_cast<const bf16x8*>(&sBl[(wc*64+n*16+l15)*32 + l16*8]);
      #pragma unroll
      for(int m=0;m<4;m++)
        #pragma unroll
        for(int n=0;n<4;n++) acc[m][n] = MFMA(ah[m], t[n], acc[m][n]);
      #pragma unroll
      for(int m=0;m<4;m++) t[m] = *reinterpret_cast<const bf16x8*>(&sAl[(wr*64+m*16+l15)*32 + l16*8]);
      #pragma unroll
      for(int m=0;m<4;m++)
        #pragma unroll
        for(int n=0;n<4;n++) acc[m][n] = MFMA(t[m], bh[n], acc[m][n]);
    }
  }
  float* Cp = C + (size_t)blockIdx.z*M*ldc;
  #pragma unroll
  for(int m=0;m<4;m++){
    int row = m0 + wr*64 + m*16 + l16*4;
    #pragma unroll
    for(int n=0;n<4;n++){
      int col = n0 + wc*64 + n*16 + l15;
      if(col < N){
        #pragma unroll
        for(int r=0;r<4;r++){
          int rrow = row + r;
          if(rrow < M) Cp[(size_t)rrow*ldc + col] = acc[m][n][r];
        }
      }
    }
  }
}

__global__ void ksum(const float* __restrict__ P, float* __restrict__ C, int n4, int z, size_t plane4){
  int i = blockIdx.x*blockDim.x + threadIdx.x;
  int st = gridDim.x*blockDim.x;
  for(; i<n4; i+=st){
    f32x4 s = reinterpret_cast<const f32x4*>(P)[i];
    for(int c=1;c<z;c++) s += reinterpret_cast<const f32x4*>(P)[(size_t)i + (size_t)c*plane4];
    reinterpret_cast<f32x4*>(C)[i] = s;
  }
}

// ---------------- norms / rope ----------------
// in = 2 split-K planes of 2048x1536, summed here
__global__ __launch_bounds__(256) void rmsnorm_qr_split(
    const float* __restrict__ in, const float* __restrict__ w,
    u16* __restrict__ hi, u16* __restrict__ lo)
{
  int s = blockIdx.x, tid = threadIdx.x;
  __shared__ float red[4];
  const float* x = in + (size_t)s*1536;
  const size_t plane = 2048ull*1536;
  float xv[6]; float ss=0.f;
  #pragma unroll
  for(int i=0;i<6;i++){ int c = tid+i*256; xv[i] = x[c] + x[plane+c]; ss += xv[i]*xv[i]; }
  #pragma unroll
  for(int o=32;o>0;o>>=1) ss += __shfl_down(ss,o,64);
  if((tid&63)==0) red[tid>>6]=ss;
  __syncthreads();
  float total = red[0]+red[1]+red[2]+red[3];
  float scale = rsqrtf(total*(1.0f/1536.0f) + 1e-6f);
  #pragma unroll
  for(int i=0;i<6;i++){
    int c = tid + i*256;
    float vv = xv[i]*scale*w[c];
    u16 hv = f2bf(vv);
    hi[(size_t)s*1536+c]=hv;
    lo[(size_t)s*1536+c]=f2bf(vv - bf2f(hv));
  }
}

__global__ __launch_bounds__(256) void kv_norm_rope(
    const float* __restrict__ kvall, const float* __restrict__ w,
    const float* __restrict__ fcos, const float* __restrict__ fsin,
    u16* __restrict__ kvb, float* __restrict__ kpe)
{
  int s = blockIdx.x, tid = threadIdx.x;
  __shared__ float red[4];
  const float* x = kvall + (size_t)s*576;
  float xv[2]; float ss=0.f;
  #pragma unroll
  for(int i=0;i<2;i++){ xv[i]=x[tid+i*256]; ss+=xv[i]*xv[i]; }
  #pragma unroll
  for(int o=32;o>0;o>>=1) ss += __shfl_down(ss,o,64);
  if((tid&63)==0) red[tid>>6]=ss;
  __syncthreads();
  float total = red[0]+red[1]+red[2]+red[3];
  float scale = rsqrtf(total*(1.0f/512.0f)+1e-6f);
  #pragma unroll
  for(int i=0;i<2;i++){ int c=tid+i*256; kvb[(size_t)s*512+c]=f2bf(xv[i]*scale*w[c]); }
  if(tid<32){
    float c0=fcos[(size_t)s*32+tid], s_=fsin[(size_t)s*32+tid];
    float x0=x[512+2*tid], x1=x[513+2*tid];
    kpe[(size_t)s*64+2*tid]   = x0*c0 - x1*s_;
    kpe[(size_t)s*64+2*tid+1] = x0*s_ + x1*c0;
  }
}

__global__ __launch_bounds__(256) void rope_q_cvt(const float* __restrict__ qpre,
    const float* __restrict__ fcos, const float* __restrict__ fsin, u16* __restrict__ qb)
{
  int s = blockIdx.x;
  const float* rowp = qpre + (size_t)s*3072;
  u16* op = qb + (size_t)s*3072;
  for(int idx=threadIdx.x; idx<3072; idx+=256){
    int hh = idx/192, d = idx - hh*192;
    float vv;
    if(d < 128) vv = rowp[hh*192 + d];
    else{
      int i2 = (d-128)>>1;
      float c0 = fcos[(size_t)s*32+i2], s_ = fsin[(size_t)s*32+i2];
      float x0 = rowp[hh*192 + 128 + 2*i2], x1 = rowp[hh*192 + 129 + 2*i2];
      vv = ((d&1)==0) ? (x0*c0 - x1*s_) : (x0*s_ + x1*c0);
    }
    op[idx] = f2bf(vv);
  }
}

__global__ __launch_bounds__(256) void qi_rope_split(const float* __restrict__ qpre,
    const float* __restrict__ fcos, const float* __restrict__ fsin,
    u16* __restrict__ hi, u16* __restrict__ lo)
{
  int s = blockIdx.x;
  const float* rowp = qpre + (size_t)s*4096;
  for(int idx=threadIdx.x; idx<4096; idx+=256){
    int hh = idx>>7, d = idx&127;
    const float* hb = rowp + (hh<<7);
    float vv;
    if(d<32){ float c0=fcos[(size_t)s*32+d], s_=fsin[(size_t)s*32+d]; vv = hb[d]*c0 - hb[d+32]*s_; }
    else if(d<64){ int i2=d-32; float c0=fcos[(size_t)s*32+i2], s_=fsin[(size_t)s*32+i2]; vv = hb[i2]*s_ + hb[d]*c0; }
    else vv = hb[d];
    u16 hv = f2bf(vv);
    hi[(size_t)s*4096+idx]=hv;
    lo[(size_t)s*4096+idx]=f2bf(vv - bf2f(hv));
  }
}

__global__ __launch_bounds__(128) void ki_ln_rope_split(
    const float* __restrict__ kpre, const float* __restrict__ w, const float* __restrict__ bb,
    const float* __restrict__ fcos, const float* __restrict__ fsin,
    u16* __restrict__ hi, u16* __restrict__ lo)
{
  int s = blockIdx.x, tid = threadIdx.x;
  __shared__ float red[2];
  __shared__ float ybuf[128];
  float x = kpre[(size_t)s*160 + tid];
  float v = x;
  #pragma unroll
  for(int o=32;o>0;o>>=1) v += __shfl_down(v,o,64);
  if((tid&63)==0) red[tid>>6]=v;
  __syncthreads();
  float mean = (red[0]+red[1])*(1.f/128.f);
  __syncthreads();
  float dx = x - mean;
  v = dx*dx;
  #pragma unroll
  for(int o=32;o>0;o>>=1) v += __shfl_down(v,o,64);
  if((tid&63)==0) red[tid>>6]=v;
  __syncthreads();
  float var = (red[0]+red[1])*(1.f/128.f);
  float y = dx*rsqrtf(var+1e-5f)*w[tid] + bb[tid];
  ybuf[tid]=y;
  __syncthreads();
  float r;
  if(tid<32){ float c0=fcos[(size_t)s*32+tid], s_=fsin[(size_t)s*32+tid]; r = ybuf[tid]*c0 - ybuf[tid+32]*s_; }
  else if(tid<64){ int i2=tid-32; float c0=fcos[(size_t)s*32+i2], s_=fsin[(size_t)s*32+i2]; r = ybuf[i2]*s_ + ybuf[tid]*c0; }
  else r = y;
  u16 hv=f2bf(r);
  hi[(size_t)s*128+tid]=hv;
  lo[(size_t)s*128+tid]=f2bf(r-bf2f(hv));
}

__global__ void assemble_k(const float* __restrict__ kvp, const float* __restrict__ kpe,
                           u16* __restrict__ kb){
  int i0 = blockIdx.x*blockDim.x + threadIdx.x;
  int st = gridDim.x*blockDim.x;
  for(int idx=i0; idx<2048*16*192; idx+=st){
    int s = idx/3072; int rrem = idx - s*3072; int hh = rrem/192; int d = rrem - hh*192;
    float val = (d<128) ? kvp[(size_t)s*4096 + hh*256 + d] : kpe[(size_t)s*64 + (d-128)];
    kb[idx] = f2bf(val);
  }
}

// transpose V: kvp[s][h*256+128+d] -> v_t[h][d][s]
__global__ __launch_bounds__(256) void transpose_v(const float* __restrict__ kvp, u16* __restrict__ vt){
  __shared__ u16 T[64*136];
  int s0 = blockIdx.x*64, h = blockIdx.y;
  int tid = threadIdx.x;
  #pragma unroll
  for(int i=0;i<8;i++){
    int ch = i*256 + tid;
    int r = ch>>5, cc = ch&31;
    f32x4 x = *reinterpret_cast<const f32x4*>(&kvp[(size_t)(s0+r)*4096 + h*256 + 128 + cc*4]);
    u16x4 y;
    #pragma unroll
    for(int j=0;j<4;j++) y[j] = f2bf(x[j]);
    *reinterpret_cast<u16x4*>(&T[r*136 + cc*4]) = y;
  }
  __syncthreads();
  #pragma unroll
  for(int i=0;i<4;i++){
    int ch = i*256 + tid;
    int d = ch>>3, sc = ch&7;
    u16x8 y;
    #pragma unroll
    for(int j=0;j<8;j++) y[j] = T[(sc*8+j)*136 + d];
    *reinterpret_cast<u16x8*>(&vt[((size_t)h*128 + d)*2048 + s0 + sc*8]) = y;
  }
}

// ---------------- fused indexer scores v3: 64x64 tiles, 528 blocks, 2 blocks/CU ----------------
DEV void isc_pass64(const u16* __restrict__ Q, const u16* __restrict__ Kb,
                    f32x4 (&sc)[2][2], int wm, int wn, int l15, int l16){
  #pragma unroll
  for(int ks=0;ks<4;ks++){
    bf16x8 a[2], b[2];
    #pragma unroll
    for(int m=0;m<2;m++){
      int row = wm*32 + m*16 + l15;
      a[m] = *reinterpret_cast<const bf16x8*>(&Q[row*128 + ((((ks<<2)+l16) ^ (row&7))<<3)]);
    }
    #pragma unroll
    for(int n=0;n<2;n++){
      int row = wn*32 + n*16 + l15;
      b[n] = *reinterpret_cast<const bf16x8*>(&Kb[row*128 + ((((ks<<2)+l16) ^ (row&7))<<3)]);
    }
    #pragma unroll
    for(int m=0;m<2;m++)
      #pragma unroll
      for(int n=0;n<2;n++) sc[m][n] = MFMA(a[m], b[n], sc[m][n]);
  }
}

__global__ __launch_bounds__(256,2) void idx_scores3(
    const u16* __restrict__ qih, const u16* __restrict__ qil,
    const u16* __restrict__ kih, const u16* __restrict__ kil,
    const float* __restrict__ wts, float* __restrict__ outp)
{
  __shared__ u16 Kh[64*128];     // 16KB
  __shared__ u16 Kl[64*128];     // 16KB
  __shared__ u16 Qb[2][64*128];  // 32KB
  int bid = blockIdx.x;
  int si=0, t=bid;
  while(t >= si+1){ t -= si+1; si++; }
  int s0 = si*64, t0 = t*64;
  int tid=threadIdx.x, w=tid>>6, l=tid&63;
  int wm=w>>1, wn=w&1, l15=l&15, l16=l>>4;
  // stage K hi+lo once (4 rounds of 4KB each)
  #pragma unroll
  for(int rnd=0;rnd<4;rnd++){
    int cid = rnd*256 + tid;
    int row = cid>>4, cc = cid&15;
    int scc = cc ^ (row&7);
    GLDS(kih + (size_t)(t0+row)*128 + scc*8, Kh + rnd*2048 + w*512);
    GLDS(kil + (size_t)(t0+row)*128 + scc*8, Kl + rnd*2048 + w*512);
  }
  // prefetch Q stage 0 (head 0, hi)
  #pragma unroll
  for(int rnd=0;rnd<4;rnd++){
    int cid = rnd*256 + tid;
    int row = cid>>4, cc = cid&15;
    int scc = cc ^ (row&7);
    GLDS(qih + (size_t)(s0+row)*4096 + scc*8, Qb[0] + rnd*2048 + w*512);
  }
  asm volatile("s_waitcnt vmcnt(0)" ::: "memory");
  __syncthreads();
  f32x4 accI[2][2], sc[2][2];
  #pragma unroll
  for(int m=0;m<2;m++) for(int n=0;n<2;n++) accI[m][n] = f32x4{0.f,0.f,0.f,0.f};
  const float cscale = 0.015625f; // HI^-0.5 * DI^-0.5
  for(int s=0;s<64;s++){
    int nxt = s+1;
    if(nxt < 64){
      const u16* src = (nxt&1) ? qil : qih;
      int hh = nxt>>1;
      u16* dst = Qb[nxt&1];
      #pragma unroll
      for(int rnd=0;rnd<4;rnd++){
        int cid = rnd*256 + tid;
        int row = cid>>4, cc = cid&15;
        int scc = cc ^ (row&7);
        GLDS(src + (size_t)(s0+row)*4096 + hh*128 + scc*8, dst + rnd*2048 + w*512);
      }
    }
    const u16* Q = Qb[s&1];
    if((s&1)==0){
      #pragma unroll
      for(int m=0;m<2;m++) for(int n=0;n<2;n++) sc[m][n] = f32x4{0.f,0.f,0.f,0.f};
      isc_pass64(Q, Kh, sc, wm, wn, l15, l16);
      isc_pass64(Q, Kl, sc, wm, wn, l15, l16);
    } else {
      isc_pass64(Q, Kh, sc, wm, wn, l15, l16);
      int hh = s>>1;
      #pragma unroll
      for(int m=0;m<2;m++)
        #pragma unroll
        for(int r=0;r<4;r++){
          float wv = wts[(size_t)(s0+wm*32+m*16+l16*4+r)*160 + 128 + hh]*cscale;
          #pragma unroll
          for(int n=0;n<2;n++) accI[m][n][r] += fmaxf(sc[m][n][r],0.f)*wv;
        }
    }
    asm volatile("s_waitcnt vmcnt(0)" ::: "memory");
    __syncthreads();
  }
  #pragma unroll
  for(int m=0;m<2;m++)
    #pragma unroll
    for(int n=0;n<2;n++)
      #pragma unroll
      for(int r=0;r<4;r++)
        outp[(size_t)(s0+wm*32+m*16+l16*4+r)*2048 + t0 + wn*32 + n*16 + l15] = accI[m][n][r];
}

// ---------------- exact top-512 per row -> bitmask ----------------
DEV uint fkey(float f){ union{float f;uint u;} v; v.f=f; return (v.u & 0x80000000u) ? ~v.u : (v.u | 0x80000000u); }

__global__ __launch_bounds__(256) void topk_mask(const float* __restrict__ scores, u64* __restrict__ bits){
  int s = blockIdx.x;
  int n = s+1;
  int tid = threadIdx.x;
  const float* row = scores + (size_t)s*2048;
  if(n <= 512){
    for(int wI=tid; wI<32; wI+=256){
      u64 m=0; int base=wI*64;
      if(base < n){ int cnt=n-base; m = (cnt>=64)? ~0ull : ((1ull<<cnt)-1ull); }
      bits[(size_t)s*32+wI]=m;
    }
    return;
  }
  __shared__ uint hist[256];
  __shared__ uint sh_B, sh_k;
  __shared__ uint wcnt[32];
  uint prefix=0, k=512;
  for(int shift=24; shift>=0; shift-=8){
    hist[tid]=0;
    __syncthreads();
    for(int t2=tid;t2<n;t2+=256){
      uint u = fkey(row[t2]);
      bool ok = (shift==24) || ((u>>(shift+8)) == (prefix>>(shift+8)));
      if(ok) atomicAdd(&hist[(u>>shift)&255u],1u);
    }
    __syncthreads();
    if(tid==0){
      uint c=0;
      for(int b2=255;b2>=0;b2--){
        c += hist[b2];
        if(c>=k){ sh_B=(uint)b2; sh_k = k-(c-hist[b2]); break; }
      }
    }
    __syncthreads();
    prefix |= sh_B<<shift;
    k = sh_k;
    __syncthreads();
  }
  uint thr = prefix;
  if(tid<32) wcnt[tid]=0;
  __syncthreads();
  int nw = (n+63)>>6;
  if(tid < nw){
    int base=tid*64, end = base+64; if(end>n) end=n;
    uint c=0;
    for(int t2=base;t2<end;t2++) if(fkey(row[t2])==thr) c++;
    wcnt[tid]=c;
  }
  __syncthreads();
  if(tid==0){
    uint runv=0;
    for(int i=0;i<32;i++){ uint c=wcnt[i]; wcnt[i]=runv; runv+=c; }
  }
  __syncthreads();
  if(tid<32){
    u64 m=0; int base=tid*64;
    if(base<n){
      uint rank = wcnt[tid];
      int end = base+64; if(end>n) end=n;
      for(int t2=base;t2<end;t2++){
        uint u = fkey(row[t2]);
        if(u>thr) m |= (1ull<<(t2-base));
        else if(u==thr){ if(rank<k) m |= (1ull<<(t2-base)); rank++; }
      }
    }
    bits[(size_t)s*32+tid]=m;
  }
}

// ---------------- flash attention v2: 64-row blocks, glds staging, V^T global ----------------
__global__ __launch_bounds__(256,3) void flash_attn(
    const u16* __restrict__ q, const u16* __restrict__ k, const u16* __restrict__ vt,
    const u64* __restrict__ bits, u16* __restrict__ o,
    u16* __restrict__ Opart, float* __restrict__ ml)
{
  __shared__ u16 Ks[64*192];
  __shared__ u16 Vt[128*64];
  __shared__ u16 Pl[64*72];
  int h = blockIdx.y;
  int pp = blockIdx.x;
  int sblk=0, chunk=0;
  for(int i=0;i<32;i++){
    int sb = 31-i; int ncc = (sb>>3)+1;
    if(pp < ncc){ sblk=sb; chunk=pp; break; }
    pp -= ncc;
  }
  int nc = (sblk>>3)+1, ntiles = sblk+1, s0 = sblk*64;
  int tid=threadIdx.x, w=tid>>6, l=tid&63;
  int l15=l&15, l16=l>>4;
  const float sscale = 0.07216878364870323f;
  bf16x8 qf[6];
  #pragma unroll
  for(int ks=0;ks<6;ks++)
    qf[ks] = *reinterpret_cast<const bf16x8*>(&q[((size_t)(s0+w*16+l15)*16 + h)*192 + ks*32 + l16*8]);
  f32x4 Oa[8];
  #pragma unroll
  for(int n=0;n<8;n++) Oa[n] = f32x4{0.f,0.f,0.f,0.f};
  float mrun[4], lrun[4];
  #pragma unroll
  for(int r=0;r<4;r++){ mrun[r]=-__builtin_inff(); lrun[r]=0.f; }
  int tt0 = chunk*8, tt1 = imin(tt0+8, ntiles);
  for(int tt=tt0; tt<tt1; tt++){
    int t0 = tt*64;
    __syncthreads();
    #pragma unroll
    for(int rnd=0;rnd<6;rnd++){
      int cid = rnd*256 + w*64 + l;
      int row = cid/24, cc = cid - row*24;
      int scc = cc ^ (row&7);
      GLDS(k + ((size_t)(t0+row)*16 + h)*192 + scc*8, Ks + rnd*2048 + w*512);
    }
    #pragma unroll
    for(int rnd=0;rnd<4;rnd++){
      int cid = rnd*256 + w*64 + l;
      int row = cid>>3, cc = cid&7;
      int scc = cc ^ (row&7);
      GLDS(vt + ((size_t)h*128 + row)*2048 + t0 + scc*8, Vt + rnd*2048 + w*512);
    }
    asm volatile("s_waitcnt vmcnt(0)" ::: "memory");
    __syncthreads();
    f32x4 S[4];
    #pragma unroll
    for(int n=0;n<4;n++) S[n] = f32x4{0.f,0.f,0.f,0.f};
    #pragma unroll
    for(int ks=0;ks<6;ks++){
      bf16x8 b[4];
      #pragma unroll
      for(int n=0;n<4;n++){
        int row = n*16+l15;
        b[n] = *reinterpret_cast<const bf16x8*>(&Ks[row*192 + ((((ks<<2)+l16) ^ (row&7))<<3)]);
      }
      #pragma unroll
      for(int n=0;n<4;n++) S[n] = MFMA(qf[ks], b[n], S[n]);
    }
    #pragma unroll
    for(int r=0;r<4;r++){
      int srow = s0 + w*16 + l16*4 + r;
      u64 wrd = bits[(size_t)srow*32 + (t0>>6)];
      float mx = -__builtin_inff();
      #pragma unroll
      for(int n=0;n<4;n++){
        int bitp = n*16 + l15;
        int tcol = t0 + bitp;
        bool ok = (tcol <= srow) && ((wrd>>bitp)&1ull);
        float val = ok ? S[n][r]*sscale : -__builtin_inff();
        S[n][r] = val;
        mx = fmaxf(mx, val);
      }
      #pragma unroll
      for(int off=1;off<16;off<<=1) mx = fmaxf(mx, __shfl_xor(mx, off, 64));
      float mold = mrun[r];
      float mnew = fmaxf(mold, mx);
      bool inf0 = (mnew == -__builtin_inff());
      float alpha = inf0 ? 1.f : __expf(mold - mnew);
      float rs = 0.f;
      #pragma unroll
      for(int n=0;n<4;n++){
        float p = inf0 ? 0.f : __expf(S[n][r] - mnew);
        S[n][r] = p;
        rs += p;
      }
      #pragma unroll
      for(int off=1;off<16;off<<=1) rs += __shfl_xor(rs, off, 64);
      mrun[r]=mnew;
      lrun[r] = lrun[r]*alpha + rs;
      #pragma unroll
      for(int n=0;n<8;n++) Oa[n][r] *= alpha;
    }
    #pragma unroll
    for(int n=0;n<4;n++)
      #pragma unroll
      for(int r=0;r<4;r++)
        Pl[(w*16+l16*4+r)*72 + n*16+l15] = f2bf(S[n][r]);
    #pragma unroll
    for(int ks=0;ks<2;ks++){
      bf16x8 a = *reinterpret_cast<const bf16x8*>(&Pl[(w*16+l15)*72 + ks*32 + l16*8]);
      bf16x8 bb[8];
      #pragma unroll
      for(int n=0;n<8;n++){
        int d = n*16+l15;
        bb[n] = *reinterpret_cast<const bf16x8*>(&Vt[d*64 + ((((ks<<2)+l16) ^ (d&7))<<3)]);
      }
      #pragma unroll
      for(int n=0;n<8;n++) Oa[n] = MFMA(a, bb[n], Oa[n]);
    }
  }
  if(nc == 1){
    #pragma unroll
    for(int r=0;r<4;r++){
      int srow = s0 + w*16 + l16*4 + r;
      float inv = 1.f/lrun[r];
      #pragma unroll
      for(int n=0;n<8;n++)
        o[(size_t)srow*2048 + h*128 + n*16 + l15] = f2bf(Oa[n][r]*inv);
    }
  } else {
    int part = ((h*32 + sblk)<<2) + chunk;
    u16* Op = Opart + (size_t)part*8192;
    #pragma unroll
    for(int r=0;r<4;r++){
      int rit = w*16 + l16*4 + r;
      #pragma unroll
      for(int n=0;n<8;n++)
        Op[rit*128 + n*16 + l15] = f2bf(Oa[n][r]);
      if(l15==0){
        ml[(size_t)part*128 + rit*2]   = mrun[r];
        ml[(size_t)part*128 + rit*2+1] = lrun[r];
      }
    }
  }
}

__global__ __launch_bounds__(256) void flash_combine(
    const u16* __restrict__ Opart, const float* __restrict__ ml, u16* __restrict__ o)
{
  int b = blockIdx.x;
  int h = b/24, sblk = 8 + (b%24);
  int nc = (sblk>>3)+1;
  int tid = threadIdx.x;
  int r = tid>>2, dq = (tid&3)*32;
  int s0 = sblk*64;
  int pbase = (h*32+sblk)<<2;
  float m[4], lv[4], wgt[4];
  float M = -__builtin_inff();
  for(int c=0;c<nc;c++){
    m[c]  = ml[(size_t)(pbase+c)*128 + r*2];
    lv[c] = ml[(size_t)(pbase+c)*128 + r*2 + 1];
    if(lv[c] > 0.f) M = fmaxf(M, m[c]);
  }
  float L = 0.f;
  for(int c=0;c<nc;c++){
    wgt[c] = (lv[c] > 0.f) ? __expf(m[c]-M) : 0.f;
    L += lv[c]*wgt[c];
  }
  float inv = 1.f/L;
  for(int dd=0; dd<32; dd+=8){
    float accv[8];
    #pragma unroll
    for(int j=0;j<8;j++) accv[j]=0.f;
    for(int c=0;c<nc;c++){
      u16x8 pv = *reinterpret_cast<const u16x8*>(&Opart[(size_t)(pbase+c)*8192 + r*128 + dq + dd]);
      #pragma unroll
      for(int j=0;j<8;j++) accv[j] += wgt[c]*bf2f(pv[j]);
    }
    u16x8 ov;
    #pragma unroll
    for(int j=0;j<8;j++) ov[j] = f2bf(accv[j]*inv);
    *reinterpret_cast<u16x8*>(&o[(size_t)(s0+r)*2048 + h*128 + dq + dd]) = ov;
  }
}

// ---------------- host ----------------
extern "C" void kernel_launch(void* const* d_in, const int* in_sizes, int n_in,
                              void* d_out, int out_size, void* d_ws, size_t ws_size,
                              hipStream_t stream)
{
  (void)in_sizes; (void)n_in; (void)out_size;
  const float* hs   = (const float*)d_in[0];
  const float* wqa  = (const float*)d_in[1];
  const float* qnw  = (const float*)d_in[2];
  const float* wqbw = (const float*)d_in[3];
  const float* wkva = (const float*)d_in[4];
  const float* kvnw = (const float*)d_in[5];
  const float* wkvb = (const float*)d_in[6];
  const float* wow  = (const float*)d_in[7];
  const float* iwqb = (const float*)d_in[8];
  const float* iwk  = (const float*)d_in[9];
  const float* iknw = (const float*)d_in[10];
  const float* iknb = (const float*)d_in[11];
  const float* iwp  = (const float*)d_in[12];
  const float* fcos = (const float*)d_in[13];
  const float* fsin = (const float*)d_in[14];
  float* outp = (float*)d_out;

  char* base = (char*)d_ws;
  size_t off = 0;
  auto alloc = [&](size_t bytes)->char*{ char* p = base+off; off += (bytes+255)&~(size_t)255; return p; };
  u16* hid_hi = (u16*)alloc(2048ull*2048*2);
  u16* hid_lo = (u16*)alloc(2048ull*2048*2);
  u16* wqa_hi = (u16*)alloc(1536ull*2048*2);
  u16* wqa_lo = (u16*)alloc(1536ull*2048*2);
  u16* wqb_b  = (u16*)alloc(3072ull*1536*2);
  u16* wkva_b = (u16*)alloc(576ull*2048*2);
  u16* wkvb_b = (u16*)alloc(4096ull*512*2);
  u16* wo_b   = (u16*)alloc(2048ull*2048*2);
  u16* iwqb_hi= (u16*)alloc(4096ull*1536*2);
  u16* iwqb_lo= (u16*)alloc(4096ull*1536*2);
  u16* kiwp_hi= (u16*)alloc(160ull*2048*2);
  u16* kiwp_lo= (u16*)alloc(160ull*2048*2);
  float* kiwp_C=(float*)alloc(2048ull*160*4);
  u16* qr_hi  = (u16*)alloc(2048ull*1536*2);
  u16* qr_lo  = (u16*)alloc(2048ull*1536*2);
  u16* kv_b   = (u16*)alloc(2048ull*512*2);
  float* kpe  = (float*)alloc(2048ull*64*4);
  u16* k_b    = (u16*)alloc(2048ull*16*192*2);
  u16* v_t    = (u16*)alloc(16ull*128*2048*2);
  u16* ki_hi  = (u16*)alloc(2048ull*128*2);
  u16* ki_lo  = (u16*)alloc(2048ull*128*2);
  u64* bits   = (u64*)alloc(2048ull*32*8);
  u16* attn_b = (u16*)alloc(2048ull*2048*2);
  float* reg1 = (float*)alloc(2048ull*4096*4);
  if(ws_size < off) return;

  // aliases (lifetime-checked)
  u16* q_b      = wqa_hi;            // spans wqa_hi+wqa_lo; wq_a dead after qr gemm
  u16* qi_hi    = hid_hi;            // spans hid_hi+hid_lo; hidden dead after kiwp gemm
  u16* qi_lo    = iwqb_hi;           // spans into iwqb_lo; idx_wq_b dead after qi gemm
  float* ml     = (float*)qr_lo;     // qr dead after qi gemm
  float* qr_pre = reg1;              // 2 planes x 2048x1536 (25.2MB)
  float* q_pre  = reg1;
  float* kva_part = reg1;            // 4 planes x 2048x576 (18.9MB)
  float* kvall  = reg1 + 5ull*1024*1024;  // 20MB offset, past kva_part
  float* kvp    = reg1;
  float* kiwp_part = reg1;
  float* qi_pre = reg1;
  float* iscore = reg1;
  u16* Opart    = (u16*)reg1;

  auto G1 = [&](const u16* A,int lda,const u16* B,int ldb,float* C,int ldc,int M,int N,int K,int z){
    dim3 g((unsigned)((N+127)/128), (unsigned)((M+127)/128), (unsigned)z);
    gemm_glds<0><<<g,256,0,stream>>>(A,nullptr,lda,B,nullptr,ldb,C,ldc,M,N,K);
  };
  auto G3 = [&](const u16* Ah,const u16* Al,int lda,const u16* Bh,const u16* Bl,int ldb,float* C,int ldc,int M,int N,int K,int z){
    dim3 g((unsigned)((N+127)/128), (unsigned)((M+127)/128), (unsigned)z);
    gemm_glds<1><<<g,256,0,stream>>>(Ah,Al,lda,Bh,Bl,ldb,C,ldc,M,N,K);
  };

  // converts
  cvt_split_v4<<<1024,256,0,stream>>>(hs, hid_hi, hid_lo, 2048*2048/4);
  cvt_split_v4<<<1024,256,0,stream>>>(wqa, wqa_hi, wqa_lo, 1536*2048/4);
  cvt_split_v4<<<1024,256,0,stream>>>(iwqb, iwqb_hi, iwqb_lo, 4096*1536/4);
  cvt_split_v4<<<256,256,0,stream>>>(iwk, kiwp_hi, kiwp_lo, 128*2048/4);
  cvt_split_v4<<<64,256,0,stream>>>(iwp, kiwp_hi+128*2048, kiwp_lo+128*2048, 32*2048/4);
  cvt_bf16_v4<<<1024,256,0,stream>>>(wqbw, wqb_b, 3072*1536/4);
  cvt_bf16_v4<<<512,256,0,stream>>>(wkva, wkva_b, 576*2048/4);
  cvt_bf16_v4<<<512,256,0,stream>>>(wkvb, wkvb_b, 4096*512/4);
  cvt_bf16_v4<<<1024,256,0,stream>>>(wow, wo_b, 2048*2048/4);

  // qr = rmsnorm(hidden @ wq_a^T), split-K z=2 with plane-sum fused into rmsnorm
  G3(hid_hi,hid_lo,2048, wqa_hi,wqa_lo,2048, qr_pre,1536, 2048,1536,2048, 2);
  rmsnorm_qr_split<<<2048,256,0,stream>>>(qr_pre, qnw, qr_hi, qr_lo);

  // q path
  G1(qr_hi,1536, wqb_b,1536, q_pre,3072, 2048,3072,1536, 1);
  rope_q_cvt<<<2048,256,0,stream>>>(q_pre, fcos, fsin, q_b);

  // kv path (split-K z=4)
  G1(hid_hi,2048, wkva_b,2048, kva_part,576, 2048,576,2048, 4);
  ksum<<<1024,256,0,stream>>>(kva_part, kvall, 2048*576/4, 4, (size_t)2048*576/4);
  kv_norm_rope<<<2048,256,0,stream>>>(kvall, kvnw, fcos, fsin, kv_b, kpe);
  G1(kv_b,512, wkvb_b,512, kvp,4096, 2048,4096,512, 1);
  assemble_k<<<1024,256,0,stream>>>(kvp, kpe, k_b);
  transpose_v<<<dim3(32,16),256,0,stream>>>(kvp, v_t);

  // indexer ki + wts packed (N=160, split-K z=8)
  G3(hid_hi,hid_lo,2048, kiwp_hi,kiwp_lo,2048, kiwp_part,160, 2048,160,2048, 8);
  ksum<<<1024,256,0,stream>>>(kiwp_part, kiwp_C, 2048*160/4, 8, (size_t)2048*160/4);
  ki_ln_rope_split<<<2048,128,0,stream>>>(kiwp_C, iknw, iknb, fcos, fsin, ki_hi, ki_lo);

  // indexer qi
  G3(qr_hi,qr_lo,1536, iwqb_hi,iwqb_lo,1536, qi_pre,4096, 2048,4096,1536, 1);
  qi_rope_split<<<2048,256,0,stream>>>(qi_pre, fcos, fsin, qi_hi, qi_lo);

  // fused index scores (64x64 tiles, 528 blocks, 2/CU) + exact top-512 mask
  idx_scores3<<<528,256,0,stream>>>(qi_hi, qi_lo, ki_hi, ki_lo, kiwp_C, iscore);
  topk_mask<<<2048,256,0,stream>>>(iscore, bits);

  // attention (64-row split-T) + combine + output projection
  flash_attn<<<dim3(80,16),256,0,stream>>>(q_b, k_b, v_t, bits, attn_b, Opart, ml);
  flash_combine<<<384,256,0,stream>>>(Opart, ml, attn_b);
  G1(attn_b,2048, wo_b,2048, outp,2048, 2048,2048,2048, 1);
}